// Round 1
// baseline (4279.406 us; speedup 1.0000x reference)
//
#include <hip/hip_runtime.h>
#include <hip/hip_bf16.h>

// Problem constants
#define T_LEN 8192
#define DMODEL 1536
#define NH 16
#define NKV 4
#define HD 96
#define KVDIM (NKV * HD)   // 384
#define W2 256             // WINDOW/2
#define NFREQ 48           // HD/2

static constexpr float SCALE = 0.10206207261596577f; // 1/sqrt(96)

// ---------------------------------------------------------------------------
// Generic fp32 tiled GEMM: C[M,N] = A[M,K] @ B[K,N], row-major.
// Requires M%64==0, N%64==0, K%16==0 (true for all our shapes).
// 256 threads, 64x64 tile, 4x4 register blocking.
// ---------------------------------------------------------------------------
__global__ __launch_bounds__(256) void gemm_tiled(
    const float* __restrict__ A, const float* __restrict__ B,
    float* __restrict__ C, int M, int N, int K) {
  __shared__ float As[16][64];
  __shared__ float Bs[16][64];
  const int tid = threadIdx.x;
  const int m0 = blockIdx.y * 64;
  const int n0 = blockIdx.x * 64;
  const int ty = tid >> 4;       // 0..15
  const int tx = tid & 15;       // 0..15
  const int a_row = tid >> 2;          // 0..63
  const int a_col = (tid & 3) * 4;     // 0,4,8,12
  const int b_row = tid >> 4;          // 0..15
  const int b_col = (tid & 15) * 4;    // 0..60

  float acc[4][4];
#pragma unroll
  for (int r = 0; r < 4; ++r)
#pragma unroll
    for (int c = 0; c < 4; ++c) acc[r][c] = 0.f;

  for (int kt = 0; kt < K; kt += 16) {
    const float4 av = *(const float4*)&A[(size_t)(m0 + a_row) * K + kt + a_col];
    As[a_col + 0][a_row] = av.x;
    As[a_col + 1][a_row] = av.y;
    As[a_col + 2][a_row] = av.z;
    As[a_col + 3][a_row] = av.w;
    const float4 bv = *(const float4*)&B[(size_t)(kt + b_row) * N + n0 + b_col];
    *(float4*)&Bs[b_row][b_col] = bv;
    __syncthreads();
#pragma unroll
    for (int kk = 0; kk < 16; ++kk) {
      const float4 a = *(const float4*)&As[kk][ty * 4];
      const float4 b = *(const float4*)&Bs[kk][tx * 4];
      const float ar[4] = {a.x, a.y, a.z, a.w};
      const float br[4] = {b.x, b.y, b.z, b.w};
#pragma unroll
      for (int r = 0; r < 4; ++r)
#pragma unroll
        for (int c = 0; c < 4; ++c)
          acc[r][c] = fmaf(ar[r], br[c], acc[r][c]);
    }
    __syncthreads();
  }
#pragma unroll
  for (int r = 0; r < 4; ++r) {
    float4 o;
    o.x = acc[r][0]; o.y = acc[r][1]; o.z = acc[r][2]; o.w = acc[r][3];
    *(float4*)&C[(size_t)(m0 + ty * 4 + r) * N + n0 + tx * 4] = o;
  }
}

// ---------------------------------------------------------------------------
// qg row 0: qg0[j] = sum_k x[0,k] * W_qg[k,j], j in [0,1536)
// ---------------------------------------------------------------------------
__global__ void qg0_kernel(const float* __restrict__ x,
                           const float* __restrict__ W,
                           float* __restrict__ qg0) {
  const int j = blockIdx.x * 256 + threadIdx.x;
  if (j >= DMODEL) return;
  float acc = 0.f;
  for (int k = 0; k < DMODEL; ++k)
    acc = fmaf(x[k], W[(size_t)k * DMODEL + j], acc);
  qg0[j] = acc;
}

// ---------------------------------------------------------------------------
// In-place interleaved RoPE on arr of shape (T, H, 96).
// pair i in [0,48): (2i, 2i+1); cos/sin tables shape (T_LEN, 48), indexed
// by position_ids[t].
// ---------------------------------------------------------------------------
__global__ void rope_ip(float* __restrict__ arr,
                        const float* __restrict__ cosf,
                        const float* __restrict__ sinf,
                        const int* __restrict__ pid, int T, int H) {
  const int idx = blockIdx.x * 256 + threadIdx.x;
  const int total = T * H * NFREQ;
  if (idx >= total) return;
  const int i = idx % NFREQ;
  const int th = idx / NFREQ;       // t*H + h
  const int t = th / H;
  const int p = pid[t];
  const float c = cosf[(size_t)p * NFREQ + i];
  const float s = sinf[(size_t)p * NFREQ + i];
  const size_t base = (size_t)th * HD + 2 * i;
  const float e = arr[base];
  const float o = arr[base + 1];
  arr[base]     = e * c - o * s;
  arr[base + 1] = e * s + o * c;
}

// ---------------------------------------------------------------------------
// Local attention: one block per (t, h). Keys p in [max(1,t-256), t] from
// ksl/vsl (kv head h/4) plus one global key = kg/vg at position 0.
// ---------------------------------------------------------------------------
__global__ __launch_bounds__(256) void local_attn_kernel(
    const float* __restrict__ qs, const float* __restrict__ ksl,
    const float* __restrict__ vsl, const float* __restrict__ kg,
    const float* __restrict__ vg, float* __restrict__ attn) {
  const int t = blockIdx.x;
  const int h = blockIdx.y;
  const int kh = h >> 2;
  const int tid = threadIdx.x;
  __shared__ float q[HD];
  __shared__ float sc[260];
  __shared__ float red[4];

  if (tid < HD) q[tid] = qs[(size_t)t * DMODEL + h * HD + tid];
  __syncthreads();

  int p_lo = t - W2; if (p_lo < 1) p_lo = 1;
  int nloc = t - p_lo + 1; if (t < 1) nloc = 0;
  const int ntot = nloc + 1;  // + global key

  float pm = -1e30f;
  for (int idx = tid; idx < ntot; idx += 256) {
    const float* kp = (idx < nloc)
        ? (ksl + (size_t)(p_lo + idx) * KVDIM + kh * HD)
        : (kg + kh * HD);   // row 0 of kg
    float d = 0.f;
#pragma unroll 16
    for (int j = 0; j < HD; ++j) d = fmaf(q[j], kp[j], d);
    d *= SCALE;
    sc[idx] = d;
    pm = fmaxf(pm, d);
  }
  // block max
#pragma unroll
  for (int off = 32; off > 0; off >>= 1) pm = fmaxf(pm, __shfl_down(pm, off));
  if ((tid & 63) == 0) red[tid >> 6] = pm;
  __syncthreads();
  const float M = fmaxf(fmaxf(red[0], red[1]), fmaxf(red[2], red[3]));
  __syncthreads();
  // exp + block sum
  float ps = 0.f;
  for (int idx = tid; idx < ntot; idx += 256) {
    const float e = __expf(sc[idx] - M);
    sc[idx] = e;
    ps += e;
  }
#pragma unroll
  for (int off = 32; off > 0; off >>= 1) ps += __shfl_down(ps, off);
  if ((tid & 63) == 0) red[tid >> 6] = ps;
  __syncthreads();
  const float S = red[0] + red[1] + red[2] + red[3];
  const float inv = 1.0f / S;
  // weighted sum of V
  if (tid < HD) {
    float acc = 0.f;
    for (int i = 0; i < nloc; ++i)
      acc = fmaf(sc[i], vsl[(size_t)(p_lo + i) * KVDIM + kh * HD + tid], acc);
    acc = fmaf(sc[nloc], vg[kh * HD + tid], acc);
    attn[(size_t)t * DMODEL + h * HD + tid] = acc * inv;
  }
}

// ---------------------------------------------------------------------------
// Global row: q = qg0[h], keys = kg (ALL 8192 positions, no causal mask),
// values = vg. Output overwrites attn row 0. One block per head.
// ---------------------------------------------------------------------------
__global__ __launch_bounds__(256) void global_attn_kernel(
    const float* __restrict__ qg0, const float* __restrict__ kg,
    const float* __restrict__ vg, float* __restrict__ attn) {
  const int h = blockIdx.x;
  const int kh = h >> 2;
  const int tid = threadIdx.x;
  __shared__ float q[HD];
  __shared__ float sc[T_LEN];
  __shared__ float red[4];

  if (tid < HD) q[tid] = qg0[h * HD + tid];
  __syncthreads();

  float pm = -1e30f;
  for (int k = tid; k < T_LEN; k += 256) {
    const float* kp = kg + (size_t)k * KVDIM + kh * HD;
    float d = 0.f;
#pragma unroll 16
    for (int j = 0; j < HD; ++j) d = fmaf(q[j], kp[j], d);
    d *= SCALE;
    sc[k] = d;
    pm = fmaxf(pm, d);
  }
#pragma unroll
  for (int off = 32; off > 0; off >>= 1) pm = fmaxf(pm, __shfl_down(pm, off));
  if ((tid & 63) == 0) red[tid >> 6] = pm;
  __syncthreads();
  const float M = fmaxf(fmaxf(red[0], red[1]), fmaxf(red[2], red[3]));
  __syncthreads();
  float ps = 0.f;
  for (int k = tid; k < T_LEN; k += 256) {
    const float e = __expf(sc[k] - M);
    sc[k] = e;
    ps += e;
  }
#pragma unroll
  for (int off = 32; off > 0; off >>= 1) ps += __shfl_down(ps, off);
  if ((tid & 63) == 0) red[tid >> 6] = ps;
  __syncthreads();
  const float S = red[0] + red[1] + red[2] + red[3];
  const float inv = 1.0f / S;
  if (tid < HD) {
    float acc = 0.f;
    for (int k = 0; k < T_LEN; ++k)
      acc = fmaf(sc[k], vg[(size_t)k * KVDIM + kh * HD + tid], acc);
    attn[h * HD + tid] = acc * inv;   // row t = 0
  }
}

// ---------------------------------------------------------------------------
// Launch
// ---------------------------------------------------------------------------
extern "C" void kernel_launch(void* const* d_in, const int* in_sizes, int n_in,
                              void* d_out, int out_size, void* d_ws, size_t ws_size,
                              hipStream_t stream) {
  const float* x     = (const float*)d_in[0];
  const float* cosf  = (const float*)d_in[1];
  const float* sinf  = (const float*)d_in[2];
  const int*   pid   = (const int*)d_in[3];
  const float* W_qs  = (const float*)d_in[4];
  const float* W_ks  = (const float*)d_in[5];
  const float* W_vs  = (const float*)d_in[6];
  const float* W_qg  = (const float*)d_in[7];
  const float* W_kg  = (const float*)d_in[8];
  const float* W_vg  = (const float*)d_in[9];
  const float* W_o   = (const float*)d_in[10];
  float* out = (float*)d_out;

  // Workspace layout (floats)
  float* ws   = (float*)d_ws;
  float* qs   = ws;                       // 8192*1536 = 12582912
  float* ksl  = qs  + (size_t)T_LEN * DMODEL;   // 8192*384
  float* vsl  = ksl + (size_t)T_LEN * KVDIM;
  float* kg   = vsl + (size_t)T_LEN * KVDIM;
  float* vg   = kg  + (size_t)T_LEN * KVDIM;
  float* qg0  = vg  + (size_t)T_LEN * KVDIM;    // 1536
  float* attn = qg0 + DMODEL;                   // 8192*1536

  const dim3 blk(256);

  // Projections
  gemm_tiled<<<dim3(DMODEL / 64, T_LEN / 64), blk, 0, stream>>>(x, W_qs, qs, T_LEN, DMODEL, DMODEL);
  gemm_tiled<<<dim3(KVDIM / 64, T_LEN / 64), blk, 0, stream>>>(x, W_ks, ksl, T_LEN, KVDIM, DMODEL);
  gemm_tiled<<<dim3(KVDIM / 64, T_LEN / 64), blk, 0, stream>>>(x, W_vs, vsl, T_LEN, KVDIM, DMODEL);
  gemm_tiled<<<dim3(KVDIM / 64, T_LEN / 64), blk, 0, stream>>>(x, W_kg, kg, T_LEN, KVDIM, DMODEL);
  gemm_tiled<<<dim3(KVDIM / 64, T_LEN / 64), blk, 0, stream>>>(x, W_vg, vg, T_LEN, KVDIM, DMODEL);
  qg0_kernel<<<(DMODEL + 255) / 256, blk, 0, stream>>>(x, W_qg, qg0);

  // RoPE (in place) on qs, ksl, kg, qg0
  {
    const int tq = T_LEN * NH * NFREQ;
    const int tk = T_LEN * NKV * NFREQ;
    rope_ip<<<(tq + 255) / 256, blk, 0, stream>>>(qs,  cosf, sinf, pid, T_LEN, NH);
    rope_ip<<<(tk + 255) / 256, blk, 0, stream>>>(ksl, cosf, sinf, pid, T_LEN, NKV);
    rope_ip<<<(tk + 255) / 256, blk, 0, stream>>>(kg,  cosf, sinf, pid, T_LEN, NKV);
    rope_ip<<<(NH * NFREQ + 255) / 256, blk, 0, stream>>>(qg0, cosf, sinf, pid, 1, NH);
  }

  // Attention
  local_attn_kernel<<<dim3(T_LEN, NH), blk, 0, stream>>>(qs, ksl, vsl, kg, vg, attn);
  global_attn_kernel<<<NH, blk, 0, stream>>>(qg0, kg, vg, attn);

  // Output projection
  gemm_tiled<<<dim3(DMODEL / 64, T_LEN / 64), blk, 0, stream>>>(attn, W_o, out, T_LEN, DMODEL, DMODEL);
}

// Round 3
// 2637.363 us; speedup vs baseline: 1.6226x; 1.6226x over previous
//
#include <hip/hip_runtime.h>
#include <hip/hip_bf16.h>

// Problem constants
#define T_LEN 8192
#define DMODEL 1536
#define NH 16
#define NKV 4
#define HD 96
#define KVDIM (NKV * HD)   // 384
#define W2 256             // WINDOW/2
#define NFREQ 48           // HD/2

static constexpr float SCALE = 0.10206207261596577f; // 1/sqrt(96)

typedef float f32x4 __attribute__((ext_vector_type(4)));
typedef float f32x2 __attribute__((ext_vector_type(2)));

// ---------------------------------------------------------------------------
// Generic fp32 tiled GEMM: C[M,N] = A[M,K] @ B[K,N], row-major.
// ---------------------------------------------------------------------------
__global__ __launch_bounds__(256) void gemm_tiled(
    const float* __restrict__ A, const float* __restrict__ B,
    float* __restrict__ C, int M, int N, int K) {
  __shared__ float As[16][64];
  __shared__ float Bs[16][64];
  const int tid = threadIdx.x;
  const int m0 = blockIdx.y * 64;
  const int n0 = blockIdx.x * 64;
  const int ty = tid >> 4;
  const int tx = tid & 15;
  const int a_row = tid >> 2;
  const int a_col = (tid & 3) * 4;
  const int b_row = tid >> 4;
  const int b_col = (tid & 15) * 4;

  float acc[4][4];
#pragma unroll
  for (int r = 0; r < 4; ++r)
#pragma unroll
    for (int c = 0; c < 4; ++c) acc[r][c] = 0.f;

  for (int kt = 0; kt < K; kt += 16) {
    const float4 av = *(const float4*)&A[(size_t)(m0 + a_row) * K + kt + a_col];
    As[a_col + 0][a_row] = av.x;
    As[a_col + 1][a_row] = av.y;
    As[a_col + 2][a_row] = av.z;
    As[a_col + 3][a_row] = av.w;
    const float4 bv = *(const float4*)&B[(size_t)(kt + b_row) * N + n0 + b_col];
    *(float4*)&Bs[b_row][b_col] = bv;
    __syncthreads();
#pragma unroll
    for (int kk = 0; kk < 16; ++kk) {
      const float4 a = *(const float4*)&As[kk][ty * 4];
      const float4 b = *(const float4*)&Bs[kk][tx * 4];
      const float ar[4] = {a.x, a.y, a.z, a.w};
      const float br[4] = {b.x, b.y, b.z, b.w};
#pragma unroll
      for (int r = 0; r < 4; ++r)
#pragma unroll
        for (int c = 0; c < 4; ++c)
          acc[r][c] = fmaf(ar[r], br[c], acc[r][c]);
    }
    __syncthreads();
  }
#pragma unroll
  for (int r = 0; r < 4; ++r) {
    float4 o;
    o.x = acc[r][0]; o.y = acc[r][1]; o.z = acc[r][2]; o.w = acc[r][3];
    *(float4*)&C[(size_t)(m0 + ty * 4 + r) * N + n0 + tx * 4] = o;
  }
}

// ---------------------------------------------------------------------------
// qg row 0
// ---------------------------------------------------------------------------
__global__ void qg0_kernel(const float* __restrict__ x,
                           const float* __restrict__ W,
                           float* __restrict__ qg0) {
  const int j = blockIdx.x * 256 + threadIdx.x;
  if (j >= DMODEL) return;
  float acc = 0.f;
  for (int k = 0; k < DMODEL; ++k)
    acc = fmaf(x[k], W[(size_t)k * DMODEL + j], acc);
  qg0[j] = acc;
}

// ---------------------------------------------------------------------------
// In-place interleaved RoPE
// ---------------------------------------------------------------------------
__global__ void rope_ip(float* __restrict__ arr,
                        const float* __restrict__ cosf,
                        const float* __restrict__ sinf,
                        const int* __restrict__ pid, int T, int H) {
  const int idx = blockIdx.x * 256 + threadIdx.x;
  const int total = T * H * NFREQ;
  if (idx >= total) return;
  const int i = idx % NFREQ;
  const int th = idx / NFREQ;
  const int t = th / H;
  const int p = pid[t];
  const float c = cosf[(size_t)p * NFREQ + i];
  const float s = sinf[(size_t)p * NFREQ + i];
  const size_t base = (size_t)th * HD + 2 * i;
  const float e = arr[base];
  const float o = arr[base + 1];
  arr[base]     = e * c - o * s;
  arr[base + 1] = e * s + o * c;
}

// ---------------------------------------------------------------------------
// Local attention v2: flash-style tiles.
// Block = 256 threads, grid (T/64, NH). Per block: 64 queries of one head.
// Key tiles of 64 staged in LDS; tiles kb = t0 - W2 + ti*64 for ti=0..4
// cover exactly the needed key range [t0-256, t0+63]. Online softmax state
// in registers (replicated across the 16 lanes of each query group); probs
// handed phase A -> phase B via LDS (same-wave rows only: Ps row qi+16r is
// written by tids qi*16..qi*16+15 and read by tid qi*16+xi — one wave).
// Global key 0 (kg/vg row 0) appended as a final register-local step.
// ---------------------------------------------------------------------------
__global__ __launch_bounds__(256) void local_attn_v2(
    const float* __restrict__ qs, const float* __restrict__ ksl,
    const float* __restrict__ vsl, const float* __restrict__ kg,
    const float* __restrict__ vg, float* __restrict__ attn) {
  // stride 100 floats: 400B rows keep float4 alignment; strided-16 row
  // ownership makes phase-A reads 2-way-conflict max (free per m136).
  __shared__ float Qs[64][100];
  __shared__ float Ks[64][100];
  __shared__ float Vs[64][100];
  __shared__ float Ps[64][68];
  __shared__ float Kg0[HD];
  __shared__ float Vg0[HD];

  const int t0 = blockIdx.x * 64;
  const int h  = blockIdx.y;
  const int kh = h >> 2;
  const int tid = threadIdx.x;
  const int qi = tid >> 4;      // 0..15: owns query rows qi+16r
  const int xi = tid & 15;      // 0..15: phase A key lanes / phase B dim group
  const int xi6 = xi * 6;

  // --- stage Q tile + global K/V row 0 ---
  {
    const int r = tid >> 2;
    const int c = tid & 3;
    const float* src = qs + (size_t)(t0 + r) * DMODEL + h * HD;
#pragma unroll
    for (int i = 0; i < 6; ++i) {
      const int j4 = c + i * 4;
      *(f32x4*)&Qs[r][j4 * 4] = *(const f32x4*)(src + j4 * 4);
    }
  }
  if (tid < HD) {
    Kg0[tid] = kg[kh * HD + tid];  // position 0: RoPE is identity
    Vg0[tid] = vg[kh * HD + tid];
  }

  float o_acc[4][6];
  float m_run[4], l_run[4];
#pragma unroll
  for (int r = 0; r < 4; ++r) {
    m_run[r] = -1e30f; l_run[r] = 0.f;
#pragma unroll
    for (int i = 0; i < 6; ++i) o_acc[r][i] = 0.f;
  }

  __syncthreads();

  for (int ti = 0; ti < 5; ++ti) {
    const int kb = t0 - W2 + ti * 64;   // key-tile base: [t0-256 .. t0]
    if (kb < 0) continue;  // fully masked tile (uniform across block)

    // --- stage K/V tile (64 rows x 96) ---
    {
      const int r = tid >> 2;
      const int c = tid & 3;
      const float* ksrc = ksl + (size_t)(kb + r) * KVDIM + kh * HD;
      const float* vsrc = vsl + (size_t)(kb + r) * KVDIM + kh * HD;
#pragma unroll
      for (int i = 0; i < 6; ++i) {
        const int j4 = c + i * 4;
        *(f32x4*)&Ks[r][j4 * 4] = *(const f32x4*)(ksrc + j4 * 4);
        *(f32x4*)&Vs[r][j4 * 4] = *(const f32x4*)(vsrc + j4 * 4);
      }
    }
    __syncthreads();

    // --- phase A: S = Q K^T, 4q x 4k per thread (strided 16) ---
    float s[4][4];
#pragma unroll
    for (int r = 0; r < 4; ++r)
#pragma unroll
      for (int c = 0; c < 4; ++c) s[r][c] = 0.f;

#pragma unroll 4
    for (int j4 = 0; j4 < 24; ++j4) {
      f32x4 q4[4], k4[4];
#pragma unroll
      for (int r = 0; r < 4; ++r) q4[r] = *(const f32x4*)&Qs[qi + 16 * r][j4 * 4];
#pragma unroll
      for (int c = 0; c < 4; ++c) k4[c] = *(const f32x4*)&Ks[xi + 16 * c][j4 * 4];
#pragma unroll
      for (int r = 0; r < 4; ++r)
#pragma unroll
        for (int c = 0; c < 4; ++c)
#pragma unroll
          for (int e = 0; e < 4; ++e)
            s[r][c] = fmaf(q4[r][e], k4[c][e], s[r][c]);
    }

    // --- mask + online softmax (state in registers, shfl across 16 lanes) ---
    float alpha[4];
#pragma unroll
    for (int r = 0; r < 4; ++r) {
      const int tq = t0 + qi + 16 * r;
      float rm = -1e30f;
#pragma unroll
      for (int c = 0; c < 4; ++c) {
        const int p = kb + xi + 16 * c;
        const bool ok = (p >= 1) && (p + W2 >= tq) && (p <= tq);
        s[r][c] = ok ? s[r][c] * SCALE : -1e30f;
        rm = fmaxf(rm, s[r][c]);
      }
#pragma unroll
      for (int mo = 1; mo < 16; mo <<= 1) rm = fmaxf(rm, __shfl_xor(rm, mo));
      const float m_new = fmaxf(m_run[r], rm);
      float psum = 0.f;
#pragma unroll
      for (int c = 0; c < 4; ++c) {
        const float pv = (s[r][c] > -1e29f) ? __expf(s[r][c] - m_new) : 0.f;
        Ps[qi + 16 * r][xi + 16 * c] = pv;
        psum += pv;
      }
#pragma unroll
      for (int mo = 1; mo < 16; mo <<= 1) psum += __shfl_xor(psum, mo);
      alpha[r] = __expf(m_run[r] - m_new);
      l_run[r] = l_run[r] * alpha[r] + psum;
      m_run[r] = m_new;
    }
    // No barrier needed: Ps rows of query group qi are written and read by
    // the same wave; DS ops are wave-ordered.

    // --- phase B: O = alpha*O + P V, 4q x 6d per thread ---
#pragma unroll
    for (int r = 0; r < 4; ++r)
#pragma unroll
      for (int i = 0; i < 6; ++i) o_acc[r][i] *= alpha[r];

#pragma unroll 2
    for (int k4 = 0; k4 < 16; ++k4) {
      f32x4 p4[4];
#pragma unroll
      for (int r = 0; r < 4; ++r)
        p4[r] = *(const f32x4*)&Ps[qi + 16 * r][k4 * 4];
#pragma unroll
      for (int kk = 0; kk < 4; ++kk) {
        const float* vrow = &Vs[k4 * 4 + kk][xi6];
        const f32x2 v0 = *(const f32x2*)(vrow);
        const f32x2 v1 = *(const f32x2*)(vrow + 2);
        const f32x2 v2 = *(const f32x2*)(vrow + 4);
#pragma unroll
        for (int r = 0; r < 4; ++r) {
          const float pr = p4[r][kk];
          o_acc[r][0] = fmaf(pr, v0[0], o_acc[r][0]);
          o_acc[r][1] = fmaf(pr, v0[1], o_acc[r][1]);
          o_acc[r][2] = fmaf(pr, v1[0], o_acc[r][2]);
          o_acc[r][3] = fmaf(pr, v1[1], o_acc[r][3]);
          o_acc[r][4] = fmaf(pr, v2[0], o_acc[r][4]);
          o_acc[r][5] = fmaf(pr, v2[1], o_acc[r][5]);
        }
      }
    }
    __syncthreads();  // protect Ks/Vs before next tile's staging
  }

  // --- global key (kg/vg row 0), always unmasked (g=0 <= t) ---
  {
    float sg[4] = {0.f, 0.f, 0.f, 0.f};
#pragma unroll 4
    for (int j4 = 0; j4 < 24; ++j4) {
      const f32x4 kj = *(const f32x4*)&Kg0[j4 * 4];
#pragma unroll
      for (int r = 0; r < 4; ++r) {
        const f32x4 qv = *(const f32x4*)&Qs[qi + 16 * r][j4 * 4];
#pragma unroll
        for (int e = 0; e < 4; ++e) sg[r] = fmaf(qv[e], kj[e], sg[r]);
      }
    }
#pragma unroll
    for (int r = 0; r < 4; ++r) {
      const float sc = sg[r] * SCALE;
      const float m_new = fmaxf(m_run[r], sc);
      const float al = __expf(m_run[r] - m_new);
      const float p  = __expf(sc - m_new);
      const float l  = l_run[r] * al + p;
      const float inv = 1.0f / l;
      float* dst = attn + (size_t)(t0 + qi + 16 * r) * DMODEL + h * HD + xi6;
#pragma unroll
      for (int i = 0; i < 6; ++i)
        dst[i] = (o_acc[r][i] * al + p * Vg0[xi6 + i]) * inv;
    }
  }
}

// ---------------------------------------------------------------------------
// Global row: q = qg0[h] attends over all 8192 kg keys; overwrites attn row 0.
// ---------------------------------------------------------------------------
__global__ __launch_bounds__(256) void global_attn_kernel(
    const float* __restrict__ qg0, const float* __restrict__ kg,
    const float* __restrict__ vg, float* __restrict__ attn) {
  const int h = blockIdx.x;
  const int kh = h >> 2;
  const int tid = threadIdx.x;
  __shared__ float q[HD];
  __shared__ float sc[T_LEN];
  __shared__ float red[4];

  if (tid < HD) q[tid] = qg0[h * HD + tid];
  __syncthreads();

  float pm = -1e30f;
  for (int k = tid; k < T_LEN; k += 256) {
    const float* kp = kg + (size_t)k * KVDIM + kh * HD;
    float d = 0.f;
#pragma unroll 16
    for (int j = 0; j < HD; ++j) d = fmaf(q[j], kp[j], d);
    d *= SCALE;
    sc[k] = d;
    pm = fmaxf(pm, d);
  }
#pragma unroll
  for (int off = 32; off > 0; off >>= 1) pm = fmaxf(pm, __shfl_down(pm, off));
  if ((tid & 63) == 0) red[tid >> 6] = pm;
  __syncthreads();
  const float M = fmaxf(fmaxf(red[0], red[1]), fmaxf(red[2], red[3]));
  __syncthreads();
  float ps = 0.f;
  for (int k = tid; k < T_LEN; k += 256) {
    const float e = __expf(sc[k] - M);
    sc[k] = e;
    ps += e;
  }
#pragma unroll
  for (int off = 32; off > 0; off >>= 1) ps += __shfl_down(ps, off);
  if ((tid & 63) == 0) red[tid >> 6] = ps;
  __syncthreads();
  const float S = red[0] + red[1] + red[2] + red[3];
  const float inv = 1.0f / S;
  if (tid < HD) {
    float acc = 0.f;
    for (int k = 0; k < T_LEN; ++k)
      acc = fmaf(sc[k], vg[(size_t)k * KVDIM + kh * HD + tid], acc);
    attn[h * HD + tid] = acc * inv;
  }
}

// ---------------------------------------------------------------------------
// Launch
// ---------------------------------------------------------------------------
extern "C" void kernel_launch(void* const* d_in, const int* in_sizes, int n_in,
                              void* d_out, int out_size, void* d_ws, size_t ws_size,
                              hipStream_t stream) {
  const float* x     = (const float*)d_in[0];
  const float* cosf  = (const float*)d_in[1];
  const float* sinf  = (const float*)d_in[2];
  const int*   pid   = (const int*)d_in[3];
  const float* W_qs  = (const float*)d_in[4];
  const float* W_ks  = (const float*)d_in[5];
  const float* W_vs  = (const float*)d_in[6];
  const float* W_qg  = (const float*)d_in[7];
  const float* W_kg  = (const float*)d_in[8];
  const float* W_vg  = (const float*)d_in[9];
  const float* W_o   = (const float*)d_in[10];
  float* out = (float*)d_out;

  float* ws   = (float*)d_ws;
  float* qs   = ws;
  float* ksl  = qs  + (size_t)T_LEN * DMODEL;
  float* vsl  = ksl + (size_t)T_LEN * KVDIM;
  float* kg   = vsl + (size_t)T_LEN * KVDIM;
  float* vg   = kg  + (size_t)T_LEN * KVDIM;
  float* qg0  = vg  + (size_t)T_LEN * KVDIM;
  float* attn = qg0 + DMODEL;

  const dim3 blk(256);

  gemm_tiled<<<dim3(DMODEL / 64, T_LEN / 64), blk, 0, stream>>>(x, W_qs, qs, T_LEN, DMODEL, DMODEL);
  gemm_tiled<<<dim3(KVDIM / 64, T_LEN / 64), blk, 0, stream>>>(x, W_ks, ksl, T_LEN, KVDIM, DMODEL);
  gemm_tiled<<<dim3(KVDIM / 64, T_LEN / 64), blk, 0, stream>>>(x, W_vs, vsl, T_LEN, KVDIM, DMODEL);
  gemm_tiled<<<dim3(KVDIM / 64, T_LEN / 64), blk, 0, stream>>>(x, W_kg, kg, T_LEN, KVDIM, DMODEL);
  gemm_tiled<<<dim3(KVDIM / 64, T_LEN / 64), blk, 0, stream>>>(x, W_vg, vg, T_LEN, KVDIM, DMODEL);
  qg0_kernel<<<(DMODEL + 255) / 256, blk, 0, stream>>>(x, W_qg, qg0);

  {
    const int tq = T_LEN * NH * NFREQ;
    const int tk = T_LEN * NKV * NFREQ;
    rope_ip<<<(tq + 255) / 256, blk, 0, stream>>>(qs,  cosf, sinf, pid, T_LEN, NH);
    rope_ip<<<(tk + 255) / 256, blk, 0, stream>>>(ksl, cosf, sinf, pid, T_LEN, NKV);
    rope_ip<<<(tk + 255) / 256, blk, 0, stream>>>(kg,  cosf, sinf, pid, T_LEN, NKV);
    rope_ip<<<(NH * NFREQ + 255) / 256, blk, 0, stream>>>(qg0, cosf, sinf, pid, 1, NH);
  }

  local_attn_v2<<<dim3(T_LEN / 64, NH), blk, 0, stream>>>(qs, ksl, vsl, kg, vg, attn);
  global_attn_kernel<<<NH, blk, 0, stream>>>(qg0, kg, vg, attn);

  gemm_tiled<<<dim3(DMODEL / 64, T_LEN / 64), blk, 0, stream>>>(attn, W_o, out, T_LEN, DMODEL, DMODEL);
}

// Round 4
// 1198.910 us; speedup vs baseline: 3.5694x; 2.1998x over previous
//
#include <hip/hip_runtime.h>

// Problem constants
#define T_LEN 8192
#define DMODEL 1536
#define NH 16
#define NKV 4
#define HD 96
#define KVDIM (NKV * HD)   // 384
#define W2 256             // WINDOW/2
#define NFREQ 48           // HD/2

static constexpr float SCALE = 0.10206207261596577f; // 1/sqrt(96)

typedef float f32x4 __attribute__((ext_vector_type(4)));
typedef float f32x2 __attribute__((ext_vector_type(2)));
typedef short short8 __attribute__((ext_vector_type(8)));
typedef unsigned short ushort;

// ---------------------------------------------------------------------------
// fp32 -> bf16 (RNE) helpers
// ---------------------------------------------------------------------------
__device__ __forceinline__ ushort f2bf(float f) {
  unsigned int x = __float_as_uint(f);
  return (ushort)((x + 0x7FFFu + ((x >> 16) & 1u)) >> 16);
}

__device__ __forceinline__ void load_lds16(const void* g, void* l) {
  __builtin_amdgcn_global_load_lds(
      (const __attribute__((address_space(1))) void*)g,
      (__attribute__((address_space(3))) void*)l, 16, 0, 0);
}

// ---------------------------------------------------------------------------
// Elementwise fp32 -> bf16 (n % 4 == 0)
// ---------------------------------------------------------------------------
__global__ __launch_bounds__(256) void convert_bf16(
    const float* __restrict__ in, ushort* __restrict__ out, int n4) {
  const int i = blockIdx.x * 256 + threadIdx.x;
  if (i >= n4) return;
  const f32x4 v = *(const f32x4*)&in[i * 4];
  ushort o[4] = {f2bf(v[0]), f2bf(v[1]), f2bf(v[2]), f2bf(v[3])};
  *(unsigned long long*)&out[i * 4] =
      (unsigned long long)o[0] | ((unsigned long long)o[1] << 16) |
      ((unsigned long long)o[2] << 32) | ((unsigned long long)o[3] << 48);
}

// ---------------------------------------------------------------------------
// W[K][N] fp32 -> Wt[N][K] bf16 (32x32 LDS tiles, K,N % 32 == 0)
// ---------------------------------------------------------------------------
__global__ __launch_bounds__(256) void transpose_bf16(
    const float* __restrict__ W, ushort* __restrict__ Wt, int K, int N) {
  __shared__ ushort tile[32][33];
  const int tx = threadIdx.x & 31;
  const int ty = threadIdx.x >> 5;          // 0..7
  const int n0 = blockIdx.x * 32;
  const int k0 = blockIdx.y * 32;
#pragma unroll
  for (int i = 0; i < 32; i += 8)
    tile[tx][ty + i] = f2bf(W[(size_t)(k0 + ty + i) * N + n0 + tx]);
  __syncthreads();
#pragma unroll
  for (int i = 0; i < 32; i += 8)
    Wt[(size_t)(n0 + ty + i) * K + k0 + tx] = tile[ty + i][tx];
}

// ---------------------------------------------------------------------------
// bf16 MFMA GEMM (m97 structure): C[M,N] = A[M,K] @ Bt[N,K]^T, fp32 out.
// Block 256 (4 waves), tile 128x128, BK=32, 16x16x32 bf16 MFMA.
// grid = (N/128, M/128, Z); Bt/C offset by z*strideBt / z*strideC.
// ---------------------------------------------------------------------------
__global__ __launch_bounds__(256) void gemm_bf16(
    const ushort* __restrict__ A, const ushort* __restrict__ Bt,
    float* __restrict__ C, int N, int K,
    size_t strideBt, size_t strideC) {
  __shared__ ushort Abuf[128 * 32];   // [row m][k] 64B rows
  __shared__ ushort Bbuf[128 * 32];   // [row n][k] 64B rows

  const ushort* BtZ = Bt + (size_t)blockIdx.z * strideBt;
  float* Cz = C + (size_t)blockIdx.z * strideC;

  const int tid  = threadIdx.x;
  const int wave = tid >> 6;
  const int lane = tid & 63;
  const int lo   = lane & 15;
  const int quad = lane >> 4;
  const int m0 = blockIdx.y * 128;
  const int n0 = blockIdx.x * 128;
  const int mw = (wave & 1) * 64;
  const int nw = (wave >> 1) * 64;

  f32x4 acc[4][4];
#pragma unroll
  for (int i = 0; i < 4; ++i)
#pragma unroll
    for (int j = 0; j < 4; ++j) acc[i][j] = {0.f, 0.f, 0.f, 0.f};

  for (int kt = 0; kt < K; kt += 32) {
    // --- stage A and Bt tiles: 128 rows x 64 B each, chunk = 16 B ---
#pragma unroll
    for (int j = 0; j < 2; ++j) {
      const int c = wave * 128 + j * 64 + lane;   // 0..511
      const int row = c >> 2;
      const int colb = (c & 3) << 4;              // byte offset in 64-B row
      const int ldsOff = (wave * 128 + j * 64) * 16;  // wave-uniform
      load_lds16((const char*)A + ((size_t)(m0 + row) * K + kt) * 2 + colb,
                 (char*)Abuf + ldsOff);
      load_lds16((const char*)BtZ + ((size_t)(n0 + row) * K + kt) * 2 + colb,
                 (char*)Bbuf + ldsOff);
    }
    __syncthreads();

    short8 af[4], bfr[4];
#pragma unroll
    for (int mt = 0; mt < 4; ++mt)
      af[mt] = *(const short8*)&Abuf[(mw + mt * 16 + lo) * 32 + quad * 8];
#pragma unroll
    for (int nt = 0; nt < 4; ++nt)
      bfr[nt] = *(const short8*)&Bbuf[(nw + nt * 16 + lo) * 32 + quad * 8];
#pragma unroll
    for (int mt = 0; mt < 4; ++mt)
#pragma unroll
      for (int nt = 0; nt < 4; ++nt)
        acc[mt][nt] = __builtin_amdgcn_mfma_f32_16x16x32_bf16(
            af[mt], bfr[nt], acc[mt][nt], 0, 0, 0);
    __syncthreads();
  }

  // Epilogue: C/D layout col=lane&15, row=quad*4+reg
#pragma unroll
  for (int mt = 0; mt < 4; ++mt) {
    const int r0 = m0 + mw + mt * 16 + quad * 4;
#pragma unroll
    for (int nt = 0; nt < 4; ++nt) {
      const int cc = n0 + nw + nt * 16 + lo;
#pragma unroll
      for (int r = 0; r < 4; ++r)
        Cz[(size_t)(r0 + r) * N + cc] = acc[mt][nt][r];
    }
  }
}

// ---------------------------------------------------------------------------
// qg row 0 (fp32)
// ---------------------------------------------------------------------------
__global__ void qg0_kernel(const float* __restrict__ x,
                           const float* __restrict__ W,
                           float* __restrict__ qg0) {
  const int j = blockIdx.x * 256 + threadIdx.x;
  if (j >= DMODEL) return;
  float acc = 0.f;
  for (int k = 0; k < DMODEL; ++k)
    acc = fmaf(x[k], W[(size_t)k * DMODEL + j], acc);
  qg0[j] = acc;
}

// ---------------------------------------------------------------------------
// In-place interleaved RoPE
// ---------------------------------------------------------------------------
__global__ void rope_ip(float* __restrict__ arr,
                        const float* __restrict__ cosf,
                        const float* __restrict__ sinf,
                        const int* __restrict__ pid, int T, int H) {
  const int idx = blockIdx.x * 256 + threadIdx.x;
  const int total = T * H * NFREQ;
  if (idx >= total) return;
  const int i = idx % NFREQ;
  const int th = idx / NFREQ;
  const int t = th / H;
  const int p = pid[t];
  const float c = cosf[(size_t)p * NFREQ + i];
  const float s = sinf[(size_t)p * NFREQ + i];
  const size_t base = (size_t)th * HD + 2 * i;
  const float e = arr[base];
  const float o = arr[base + 1];
  arr[base]     = e * c - o * s;
  arr[base + 1] = e * s + o * c;
}

// ---------------------------------------------------------------------------
// Local attention (flash-style tiles) — unchanged from round 3 (verified).
// ---------------------------------------------------------------------------
__global__ __launch_bounds__(256) void local_attn_v2(
    const float* __restrict__ qs, const float* __restrict__ ksl,
    const float* __restrict__ vsl, const float* __restrict__ kg,
    const float* __restrict__ vg, float* __restrict__ attn) {
  __shared__ float Qs[64][100];
  __shared__ float Ks[64][100];
  __shared__ float Vs[64][100];
  __shared__ float Ps[64][68];
  __shared__ float Kg0[HD];
  __shared__ float Vg0[HD];

  const int t0 = blockIdx.x * 64;
  const int h  = blockIdx.y;
  const int kh = h >> 2;
  const int tid = threadIdx.x;
  const int qi = tid >> 4;
  const int xi = tid & 15;
  const int xi6 = xi * 6;

  {
    const int r = tid >> 2;
    const int c = tid & 3;
    const float* src = qs + (size_t)(t0 + r) * DMODEL + h * HD;
#pragma unroll
    for (int i = 0; i < 6; ++i) {
      const int j4 = c + i * 4;
      *(f32x4*)&Qs[r][j4 * 4] = *(const f32x4*)(src + j4 * 4);
    }
  }
  if (tid < HD) {
    Kg0[tid] = kg[kh * HD + tid];
    Vg0[tid] = vg[kh * HD + tid];
  }

  float o_acc[4][6];
  float m_run[4], l_run[4];
#pragma unroll
  for (int r = 0; r < 4; ++r) {
    m_run[r] = -1e30f; l_run[r] = 0.f;
#pragma unroll
    for (int i = 0; i < 6; ++i) o_acc[r][i] = 0.f;
  }

  __syncthreads();

  for (int ti = 0; ti < 5; ++ti) {
    const int kb = t0 - W2 + ti * 64;
    if (kb < 0) continue;

    {
      const int r = tid >> 2;
      const int c = tid & 3;
      const float* ksrc = ksl + (size_t)(kb + r) * KVDIM + kh * HD;
      const float* vsrc = vsl + (size_t)(kb + r) * KVDIM + kh * HD;
#pragma unroll
      for (int i = 0; i < 6; ++i) {
        const int j4 = c + i * 4;
        *(f32x4*)&Ks[r][j4 * 4] = *(const f32x4*)(ksrc + j4 * 4);
        *(f32x4*)&Vs[r][j4 * 4] = *(const f32x4*)(vsrc + j4 * 4);
      }
    }
    __syncthreads();

    float s[4][4];
#pragma unroll
    for (int r = 0; r < 4; ++r)
#pragma unroll
      for (int c = 0; c < 4; ++c) s[r][c] = 0.f;

#pragma unroll 4
    for (int j4 = 0; j4 < 24; ++j4) {
      f32x4 q4[4], k4[4];
#pragma unroll
      for (int r = 0; r < 4; ++r) q4[r] = *(const f32x4*)&Qs[qi + 16 * r][j4 * 4];
#pragma unroll
      for (int c = 0; c < 4; ++c) k4[c] = *(const f32x4*)&Ks[xi + 16 * c][j4 * 4];
#pragma unroll
      for (int r = 0; r < 4; ++r)
#pragma unroll
        for (int c = 0; c < 4; ++c)
#pragma unroll
          for (int e = 0; e < 4; ++e)
            s[r][c] = fmaf(q4[r][e], k4[c][e], s[r][c]);
    }

    float alpha[4];
#pragma unroll
    for (int r = 0; r < 4; ++r) {
      const int tq = t0 + qi + 16 * r;
      float rm = -1e30f;
#pragma unroll
      for (int c = 0; c < 4; ++c) {
        const int p = kb + xi + 16 * c;
        const bool ok = (p >= 1) && (p + W2 >= tq) && (p <= tq);
        s[r][c] = ok ? s[r][c] * SCALE : -1e30f;
        rm = fmaxf(rm, s[r][c]);
      }
#pragma unroll
      for (int mo = 1; mo < 16; mo <<= 1) rm = fmaxf(rm, __shfl_xor(rm, mo));
      const float m_new = fmaxf(m_run[r], rm);
      float psum = 0.f;
#pragma unroll
      for (int c = 0; c < 4; ++c) {
        const float pv = (s[r][c] > -1e29f) ? __expf(s[r][c] - m_new) : 0.f;
        Ps[qi + 16 * r][xi + 16 * c] = pv;
        psum += pv;
      }
#pragma unroll
      for (int mo = 1; mo < 16; mo <<= 1) psum += __shfl_xor(psum, mo);
      alpha[r] = __expf(m_run[r] - m_new);
      l_run[r] = l_run[r] * alpha[r] + psum;
      m_run[r] = m_new;
    }

#pragma unroll
    for (int r = 0; r < 4; ++r)
#pragma unroll
      for (int i = 0; i < 6; ++i) o_acc[r][i] *= alpha[r];

#pragma unroll 2
    for (int k4 = 0; k4 < 16; ++k4) {
      f32x4 p4[4];
#pragma unroll
      for (int r = 0; r < 4; ++r)
        p4[r] = *(const f32x4*)&Ps[qi + 16 * r][k4 * 4];
#pragma unroll
      for (int kk = 0; kk < 4; ++kk) {
        const float* vrow = &Vs[k4 * 4 + kk][xi6];
        const f32x2 v0 = *(const f32x2*)(vrow);
        const f32x2 v1 = *(const f32x2*)(vrow + 2);
        const f32x2 v2 = *(const f32x2*)(vrow + 4);
#pragma unroll
        for (int r = 0; r < 4; ++r) {
          const float pr = p4[r][kk];
          o_acc[r][0] = fmaf(pr, v0[0], o_acc[r][0]);
          o_acc[r][1] = fmaf(pr, v0[1], o_acc[r][1]);
          o_acc[r][2] = fmaf(pr, v1[0], o_acc[r][2]);
          o_acc[r][3] = fmaf(pr, v1[1], o_acc[r][3]);
          o_acc[r][4] = fmaf(pr, v2[0], o_acc[r][4]);
          o_acc[r][5] = fmaf(pr, v2[1], o_acc[r][5]);
        }
      }
    }
    __syncthreads();
  }

  {
    float sg[4] = {0.f, 0.f, 0.f, 0.f};
#pragma unroll 4
    for (int j4 = 0; j4 < 24; ++j4) {
      const f32x4 kj = *(const f32x4*)&Kg0[j4 * 4];
#pragma unroll
      for (int r = 0; r < 4; ++r) {
        const f32x4 qv = *(const f32x4*)&Qs[qi + 16 * r][j4 * 4];
#pragma unroll
        for (int e = 0; e < 4; ++e) sg[r] = fmaf(qv[e], kj[e], sg[r]);
      }
    }
#pragma unroll
    for (int r = 0; r < 4; ++r) {
      const float sc = sg[r] * SCALE;
      const float m_new = fmaxf(m_run[r], sc);
      const float al = __expf(m_run[r] - m_new);
      const float p  = __expf(sc - m_new);
      const float l  = l_run[r] * al + p;
      const float inv = 1.0f / l;
      float* dst = attn + (size_t)(t0 + qi + 16 * r) * DMODEL + h * HD + xi6;
#pragma unroll
      for (int i = 0; i < 6; ++i)
        dst[i] = (o_acc[r][i] * al + p * Vg0[xi6 + i]) * inv;
    }
  }
}

// ---------------------------------------------------------------------------
// Global row
// ---------------------------------------------------------------------------
__global__ __launch_bounds__(256) void global_attn_kernel(
    const float* __restrict__ qg0, const float* __restrict__ kg,
    const float* __restrict__ vg, float* __restrict__ attn) {
  const int h = blockIdx.x;
  const int kh = h >> 2;
  const int tid = threadIdx.x;
  __shared__ float q[HD];
  __shared__ float sc[T_LEN];
  __shared__ float red[4];

  if (tid < HD) q[tid] = qg0[h * HD + tid];
  __syncthreads();

  float pm = -1e30f;
  for (int k = tid; k < T_LEN; k += 256) {
    const float* kp = kg + (size_t)k * KVDIM + kh * HD;
    float d = 0.f;
#pragma unroll 16
    for (int j = 0; j < HD; ++j) d = fmaf(q[j], kp[j], d);
    d *= SCALE;
    sc[k] = d;
    pm = fmaxf(pm, d);
  }
#pragma unroll
  for (int off = 32; off > 0; off >>= 1) pm = fmaxf(pm, __shfl_down(pm, off));
  if ((tid & 63) == 0) red[tid >> 6] = pm;
  __syncthreads();
  const float M = fmaxf(fmaxf(red[0], red[1]), fmaxf(red[2], red[3]));
  __syncthreads();
  float ps = 0.f;
  for (int k = tid; k < T_LEN; k += 256) {
    const float e = __expf(sc[k] - M);
    sc[k] = e;
    ps += e;
  }
#pragma unroll
  for (int off = 32; off > 0; off >>= 1) ps += __shfl_down(ps, off);
  if ((tid & 63) == 0) red[tid >> 6] = ps;
  __syncthreads();
  const float S = red[0] + red[1] + red[2] + red[3];
  const float inv = 1.0f / S;
  if (tid < HD) {
    float acc = 0.f;
    for (int k = 0; k < T_LEN; ++k)
      acc = fmaf(sc[k], vg[(size_t)k * KVDIM + kh * HD + tid], acc);
    attn[h * HD + tid] = acc * inv;
  }
}

// ---------------------------------------------------------------------------
// Launch
// ---------------------------------------------------------------------------
extern "C" void kernel_launch(void* const* d_in, const int* in_sizes, int n_in,
                              void* d_out, int out_size, void* d_ws, size_t ws_size,
                              hipStream_t stream) {
  const float* x     = (const float*)d_in[0];
  const float* cosf  = (const float*)d_in[1];
  const float* sinf  = (const float*)d_in[2];
  const int*   pid   = (const int*)d_in[3];
  const float* W_qs  = (const float*)d_in[4];
  const float* W_ks  = (const float*)d_in[5];
  const float* W_vs  = (const float*)d_in[6];
  const float* W_qg  = (const float*)d_in[7];
  const float* W_kg  = (const float*)d_in[8];
  const float* W_vg  = (const float*)d_in[9];
  const float* W_o   = (const float*)d_in[10];
  float* out = (float*)d_out;

  // Workspace (256-B aligned slices)
  char* p = (char*)d_ws;
  auto alloc = [&](size_t bytes) { char* r = p; p += (bytes + 255) & ~(size_t)255; return r; };
  float*  qs     = (float*)alloc((size_t)T_LEN * DMODEL * 4);
  float*  ksl    = (float*)alloc((size_t)T_LEN * KVDIM * 4 * 4); // ksl,vsl,kg,vg contiguous
  float*  vsl    = ksl + (size_t)T_LEN * KVDIM;
  float*  kg     = vsl + (size_t)T_LEN * KVDIM;
  float*  vg     = kg  + (size_t)T_LEN * KVDIM;
  float*  qg0    = (float*)alloc(DMODEL * 4);
  float*  attn   = (float*)alloc((size_t)T_LEN * DMODEL * 4);
  ushort* x_bf   = (ushort*)alloc((size_t)T_LEN * DMODEL * 2);
  ushort* attnbf = (ushort*)alloc((size_t)T_LEN * DMODEL * 2);
  ushort* Wqs_t  = (ushort*)alloc((size_t)DMODEL * DMODEL * 2);
  ushort* Wo_t   = (ushort*)alloc((size_t)DMODEL * DMODEL * 2);
  ushort* Wsml_t = (ushort*)alloc((size_t)4 * KVDIM * DMODEL * 2); // ks,vs,kg,vg

  const dim3 blk(256);
  const int nX4 = (T_LEN * DMODEL) / 4;

  // --- bf16 conversions / transposes ---
  convert_bf16<<<(nX4 + 255) / 256, blk, 0, stream>>>(x, x_bf, nX4);
  transpose_bf16<<<dim3(DMODEL / 32, DMODEL / 32), blk, 0, stream>>>(W_qs, Wqs_t, DMODEL, DMODEL);
  transpose_bf16<<<dim3(DMODEL / 32, DMODEL / 32), blk, 0, stream>>>(W_o,  Wo_t,  DMODEL, DMODEL);
  transpose_bf16<<<dim3(KVDIM / 32, DMODEL / 32), blk, 0, stream>>>(W_ks, Wsml_t + 0 * (size_t)KVDIM * DMODEL, DMODEL, KVDIM);
  transpose_bf16<<<dim3(KVDIM / 32, DMODEL / 32), blk, 0, stream>>>(W_vs, Wsml_t + 1 * (size_t)KVDIM * DMODEL, DMODEL, KVDIM);
  transpose_bf16<<<dim3(KVDIM / 32, DMODEL / 32), blk, 0, stream>>>(W_kg, Wsml_t + 2 * (size_t)KVDIM * DMODEL, DMODEL, KVDIM);
  transpose_bf16<<<dim3(KVDIM / 32, DMODEL / 32), blk, 0, stream>>>(W_vg, Wsml_t + 3 * (size_t)KVDIM * DMODEL, DMODEL, KVDIM);

  // --- projections (bf16 MFMA) ---
  gemm_bf16<<<dim3(DMODEL / 128, T_LEN / 128, 1), blk, 0, stream>>>(
      x_bf, Wqs_t, qs, DMODEL, DMODEL, 0, 0);
  gemm_bf16<<<dim3(KVDIM / 128, T_LEN / 128, 4), blk, 0, stream>>>(
      x_bf, Wsml_t, ksl, KVDIM, DMODEL,
      (size_t)KVDIM * DMODEL, (size_t)T_LEN * KVDIM);
  qg0_kernel<<<(DMODEL + 255) / 256, blk, 0, stream>>>(x, W_qg, qg0);

  // --- RoPE ---
  {
    const int tq = T_LEN * NH * NFREQ;
    const int tk = T_LEN * NKV * NFREQ;
    rope_ip<<<(tq + 255) / 256, blk, 0, stream>>>(qs,  cosf, sinf, pid, T_LEN, NH);
    rope_ip<<<(tk + 255) / 256, blk, 0, stream>>>(ksl, cosf, sinf, pid, T_LEN, NKV);
    rope_ip<<<(tk + 255) / 256, blk, 0, stream>>>(kg,  cosf, sinf, pid, T_LEN, NKV);
    rope_ip<<<(NH * NFREQ + 255) / 256, blk, 0, stream>>>(qg0, cosf, sinf, pid, 1, NH);
  }

  // --- attention ---
  local_attn_v2<<<dim3(T_LEN / 64, NH), blk, 0, stream>>>(qs, ksl, vsl, kg, vg, attn);
  global_attn_kernel<<<NH, blk, 0, stream>>>(qg0, kg, vg, attn);

  // --- output projection (bf16 MFMA) ---
  convert_bf16<<<(nX4 + 255) / 256, blk, 0, stream>>>(attn, attnbf, nX4);
  gemm_bf16<<<dim3(DMODEL / 128, T_LEN / 128, 1), blk, 0, stream>>>(
      attnbf, Wo_t, out, DMODEL, DMODEL, 0, 0);
}

// Round 5
// 610.671 us; speedup vs baseline: 7.0077x; 1.9633x over previous
//
#include <hip/hip_runtime.h>

// Problem constants
#define T_LEN 8192
#define DMODEL 1536
#define NH 16
#define NKV 4
#define HD 96
#define KVDIM (NKV * HD)   // 384
#define W2 256             // WINDOW/2
#define NFREQ 48           // HD/2
#define NGB 32             // global-attention split-k blocks per head

static constexpr float SCALE = 0.10206207261596577f; // 1/sqrt(96)

typedef float f32x4 __attribute__((ext_vector_type(4)));
typedef float f32x2 __attribute__((ext_vector_type(2)));
typedef short short8 __attribute__((ext_vector_type(8)));
typedef unsigned short ushort;

__device__ __forceinline__ ushort f2bf(float f) {
  unsigned int x = __float_as_uint(f);
  return (ushort)((x + 0x7FFFu + ((x >> 16) & 1u)) >> 16);
}
__device__ __forceinline__ float bf2f(ushort u) {
  return __uint_as_float((unsigned int)u << 16);
}
__device__ __forceinline__ void load_lds16(const void* g, void* l) {
  __builtin_amdgcn_global_load_lds(
      (const __attribute__((address_space(1))) void*)g,
      (__attribute__((address_space(3))) void*)l, 16, 0, 0);
}

// ---------------------------------------------------------------------------
// Elementwise fp32 -> bf16 (n4 = n/4)
// ---------------------------------------------------------------------------
__global__ __launch_bounds__(256) void convert_bf16(
    const float* __restrict__ in, ushort* __restrict__ out, int n4) {
  const int i = blockIdx.x * 256 + threadIdx.x;
  if (i >= n4) return;
  const f32x4 v = *(const f32x4*)&in[i * 4];
  ushort o[4] = {f2bf(v[0]), f2bf(v[1]), f2bf(v[2]), f2bf(v[3])};
  *(unsigned long long*)&out[i * 4] =
      (unsigned long long)o[0] | ((unsigned long long)o[1] << 16) |
      ((unsigned long long)o[2] << 32) | ((unsigned long long)o[3] << 48);
}

// ---------------------------------------------------------------------------
// W[K][N] fp32 -> Wt[N][K] bf16
// ---------------------------------------------------------------------------
__global__ __launch_bounds__(256) void transpose_bf16(
    const float* __restrict__ W, ushort* __restrict__ Wt, int K, int N) {
  __shared__ ushort tile[32][33];
  const int tx = threadIdx.x & 31;
  const int ty = threadIdx.x >> 5;
  const int n0 = blockIdx.x * 32;
  const int k0 = blockIdx.y * 32;
#pragma unroll
  for (int i = 0; i < 32; i += 8)
    tile[tx][ty + i] = f2bf(W[(size_t)(k0 + ty + i) * N + n0 + tx]);
  __syncthreads();
#pragma unroll
  for (int i = 0; i < 32; i += 8)
    Wt[(size_t)(n0 + ty + i) * K + k0 + tx] = tile[ty + i][tx];
}

// ---------------------------------------------------------------------------
// bf16 MFMA GEMM (m97 structure): C[M,N] = A @ Bt^T, fp32 out.
// ---------------------------------------------------------------------------
__global__ __launch_bounds__(256) void gemm_bf16(
    const ushort* __restrict__ A, const ushort* __restrict__ Bt,
    float* __restrict__ C, int N, int K,
    size_t strideBt, size_t strideC) {
  __shared__ ushort Abuf[128 * 32];
  __shared__ ushort Bbuf[128 * 32];

  const ushort* BtZ = Bt + (size_t)blockIdx.z * strideBt;
  float* Cz = C + (size_t)blockIdx.z * strideC;

  const int tid  = threadIdx.x;
  const int wave = tid >> 6;
  const int lane = tid & 63;
  const int lo   = lane & 15;
  const int quad = lane >> 4;
  const int m0 = blockIdx.y * 128;
  const int n0 = blockIdx.x * 128;
  const int mw = (wave & 1) * 64;
  const int nw = (wave >> 1) * 64;

  f32x4 acc[4][4];
#pragma unroll
  for (int i = 0; i < 4; ++i)
#pragma unroll
    for (int j = 0; j < 4; ++j) acc[i][j] = {0.f, 0.f, 0.f, 0.f};

  for (int kt = 0; kt < K; kt += 32) {
#pragma unroll
    for (int j = 0; j < 2; ++j) {
      const int c = wave * 128 + j * 64 + lane;
      const int row = c >> 2;
      const int colb = (c & 3) << 4;
      const int ldsOff = (wave * 128 + j * 64) * 16;
      load_lds16((const char*)A + ((size_t)(m0 + row) * K + kt) * 2 + colb,
                 (char*)Abuf + ldsOff);
      load_lds16((const char*)BtZ + ((size_t)(n0 + row) * K + kt) * 2 + colb,
                 (char*)Bbuf + ldsOff);
    }
    __syncthreads();

    short8 af[4], bfr[4];
#pragma unroll
    for (int mt = 0; mt < 4; ++mt)
      af[mt] = *(const short8*)&Abuf[(mw + mt * 16 + lo) * 32 + quad * 8];
#pragma unroll
    for (int nt = 0; nt < 4; ++nt)
      bfr[nt] = *(const short8*)&Bbuf[(nw + nt * 16 + lo) * 32 + quad * 8];
#pragma unroll
    for (int mt = 0; mt < 4; ++mt)
#pragma unroll
      for (int nt = 0; nt < 4; ++nt)
        acc[mt][nt] = __builtin_amdgcn_mfma_f32_16x16x32_bf16(
            af[mt], bfr[nt], acc[mt][nt], 0, 0, 0);
    __syncthreads();
  }

#pragma unroll
  for (int mt = 0; mt < 4; ++mt) {
    const int r0 = m0 + mw + mt * 16 + quad * 4;
#pragma unroll
    for (int nt = 0; nt < 4; ++nt) {
      const int cc = n0 + nw + nt * 16 + lo;
#pragma unroll
      for (int r = 0; r < 4; ++r)
        Cz[(size_t)(r0 + r) * N + cc] = acc[mt][nt][r];
    }
  }
}

// ---------------------------------------------------------------------------
// qg row 0 (fp32)
// ---------------------------------------------------------------------------
__global__ void qg0_kernel(const float* __restrict__ x,
                           const float* __restrict__ W,
                           float* __restrict__ qg0) {
  const int j = blockIdx.x * 256 + threadIdx.x;
  if (j >= DMODEL) return;
  float acc = 0.f;
  for (int k = 0; k < DMODEL; ++k)
    acc = fmaf(x[k], W[(size_t)k * DMODEL + j], acc);
  qg0[j] = acc;
}

// ---------------------------------------------------------------------------
// In-place interleaved RoPE (fp32)
// ---------------------------------------------------------------------------
__global__ void rope_ip(float* __restrict__ arr,
                        const float* __restrict__ cosf,
                        const float* __restrict__ sinf,
                        const int* __restrict__ pid, int T, int H) {
  const int idx = blockIdx.x * 256 + threadIdx.x;
  const int total = T * H * NFREQ;
  if (idx >= total) return;
  const int i = idx % NFREQ;
  const int th = idx / NFREQ;
  const int t = th / H;
  const int p = pid[t];
  const float c = cosf[(size_t)p * NFREQ + i];
  const float s = sinf[(size_t)p * NFREQ + i];
  const size_t base = (size_t)th * HD + 2 * i;
  const float e = arr[base];
  const float o = arr[base + 1];
  arr[base]     = e * c - o * s;
  arr[base + 1] = e * s + o * c;
}

// ---------------------------------------------------------------------------
// RoPE fp32 src -> bf16 dst (same mapping; writes a u16 pair as one u32)
// ---------------------------------------------------------------------------
__global__ void rope_conv(const float* __restrict__ src,
                          ushort* __restrict__ dst,
                          const float* __restrict__ cosf,
                          const float* __restrict__ sinf,
                          const int* __restrict__ pid, int T, int H) {
  const int idx = blockIdx.x * 256 + threadIdx.x;
  const int total = T * H * NFREQ;
  if (idx >= total) return;
  const int i = idx % NFREQ;
  const int th = idx / NFREQ;
  const int t = th / H;
  const int p = pid[t];
  const float c = cosf[(size_t)p * NFREQ + i];
  const float s = sinf[(size_t)p * NFREQ + i];
  const size_t base = (size_t)th * HD + 2 * i;
  const float e = src[base];
  const float o = src[base + 1];
  const float re = e * c - o * s;
  const float ro = e * s + o * c;
  *(unsigned int*)&dst[base] =
      (unsigned int)f2bf(re) | ((unsigned int)f2bf(ro) << 16);
}

// ---------------------------------------------------------------------------
// Local attention v3: MFMA bf16 flash tiles.
// Block 256 = 4 waves; grid (T/64, NH). Wave w owns queries t0+w*16..+15.
// LDS panels use the m97 layout: [rows][32 elems] with 64-B rows so all
// fragment reads are aligned ds_read_b128.
// ---------------------------------------------------------------------------
__global__ __launch_bounds__(256) void local_attn_v3(
    const ushort* __restrict__ qbf, const ushort* __restrict__ kbf,
    const ushort* __restrict__ vbf, const float* __restrict__ kg,
    const float* __restrict__ vg, ushort* __restrict__ obf) {
  __shared__ ushort Qb[3 * 64 * 32];   // panel p: dims [32p,32p+32)
  __shared__ ushort Kb[3 * 64 * 32];
  __shared__ ushort Vt[2 * 96 * 32];   // panel kp: V^T dims x keys[32kp..)
  __shared__ ushort Pb[4][2 * 16 * 32];// per-wave P, A-layout panels
  __shared__ float Kg0[HD];
  __shared__ float Vg0[HD];

  const int t0 = blockIdx.x * 64;
  const int h  = blockIdx.y;
  const int kh = h >> 2;
  const int tid = threadIdx.x;
  const int w    = tid >> 6;
  const int lane = tid & 63;
  const int lo   = lane & 15;
  const int quad = lane >> 4;

  // --- stage Q (once): 3 chunks of 16B per thread, panel j per chunk ---
  {
    const int rem = w * 64 + lane;        // 0..255
    const int row = rem >> 2;             // 0..63
    const int sub = (rem & 3) * 8;        // dim sub-offset within panel
#pragma unroll
    for (int j = 0; j < 3; ++j) {
      load_lds16(qbf + (size_t)(t0 + row) * DMODEL + h * HD + j * 32 + sub,
                 (char*)Qb + (j * 256 + w * 64) * 16);
    }
  }
  if (tid < HD) {
    Kg0[tid] = kg[kh * HD + tid];   // row 0; RoPE at pos 0 is identity
    Vg0[tid] = vg[kh * HD + tid];
  }

  f32x4 O[6];
#pragma unroll
  for (int i = 0; i < 6; ++i) O[i] = {0.f, 0.f, 0.f, 0.f};
  float m_run[4], l_run[4];
#pragma unroll
  for (int r = 0; r < 4; ++r) { m_run[r] = -1e30f; l_run[r] = 0.f; }

  __syncthreads();

  for (int ti = 0; ti < 5; ++ti) {
    const int kb = t0 - W2 + ti * 64;
    if (kb < 0) continue;   // uniform across block

    // --- stage K panels (global_load_lds) + Vt transpose (VGPR path) ---
    {
      const int rem = w * 64 + lane;
      const int row = rem >> 2;
      const int sub = (rem & 3) * 8;
#pragma unroll
      for (int j = 0; j < 3; ++j) {
        load_lds16(kbf + (size_t)(kb + row) * KVDIM + kh * HD + j * 32 + sub,
                   (char*)Kb + (j * 256 + w * 64) * 16);
      }
      const int key = tid & 63;
      const int dg  = tid >> 6;           // 0..3 -> dims dg*24..+23
      const ushort* vsrc = vbf + (size_t)(kb + key) * KVDIM + kh * HD + dg * 24;
      short8 v0 = *(const short8*)(vsrc);
      short8 v1 = *(const short8*)(vsrc + 8);
      short8 v2 = *(const short8*)(vsrc + 16);
      const int vbase = (key >> 5) * (96 * 32) + (key & 31);
#pragma unroll
      for (int i = 0; i < 8; ++i) {
        Vt[vbase + (dg * 24 + i) * 32]      = (ushort)v0[i];
        Vt[vbase + (dg * 24 + 8 + i) * 32]  = (ushort)v1[i];
        Vt[vbase + (dg * 24 + 16 + i) * 32] = (ushort)v2[i];
      }
    }
    __syncthreads();

    // --- QK^T: S[16q x 64k] per wave ---
    short8 af[3];
#pragma unroll
    for (int p = 0; p < 3; ++p)
      af[p] = *(const short8*)&Qb[p * 2048 + (w * 16 + lo) * 32 + quad * 8];
    f32x4 s4[4];
#pragma unroll
    for (int nt = 0; nt < 4; ++nt) s4[nt] = {0.f, 0.f, 0.f, 0.f};
#pragma unroll
    for (int nt = 0; nt < 4; ++nt)
#pragma unroll
      for (int p = 0; p < 3; ++p) {
        const short8 bf8 =
            *(const short8*)&Kb[p * 2048 + (nt * 16 + lo) * 32 + quad * 8];
        s4[nt] = __builtin_amdgcn_mfma_f32_16x16x32_bf16(af[p], bf8, s4[nt], 0, 0, 0);
      }

    // --- mask + online softmax; P -> Pb (bf16, A-layout) ---
    float alpha[4];
#pragma unroll
    for (int r = 0; r < 4; ++r) {
      const int tq = t0 + w * 16 + quad * 4 + r;
      float sv[4], rm = -1e30f;
#pragma unroll
      for (int nt = 0; nt < 4; ++nt) {
        const int p = kb + nt * 16 + lo;
        const bool ok = (p >= 1) && (p <= tq) && (p + W2 >= tq);
        sv[nt] = ok ? s4[nt][r] * SCALE : -1e30f;
        rm = fmaxf(rm, sv[nt]);
      }
#pragma unroll
      for (int mo = 1; mo < 16; mo <<= 1) rm = fmaxf(rm, __shfl_xor(rm, mo));
      const float m_new = fmaxf(m_run[r], rm);
      float psum = 0.f;
#pragma unroll
      for (int nt = 0; nt < 4; ++nt) {
        const float pv = (sv[nt] > -1e29f) ? __expf(sv[nt] - m_new) : 0.f;
        Pb[w][(nt >> 1) * 512 + (quad * 4 + r) * 32 + (nt & 1) * 16 + lo] = f2bf(pv);
        psum += pv;
      }
#pragma unroll
      for (int mo = 1; mo < 16; mo <<= 1) psum += __shfl_xor(psum, mo);
      alpha[r] = __expf(m_run[r] - m_new);
      l_run[r] = l_run[r] * alpha[r] + psum;
      m_run[r] = m_new;
    }
    // Pb written and read by the same wave; DS ops are wave-ordered.

    // --- PV: O[16q x 96d] += P @ V ---
#pragma unroll
    for (int nt6 = 0; nt6 < 6; ++nt6)
#pragma unroll
      for (int r = 0; r < 4; ++r) O[nt6][r] *= alpha[r];

    short8 pa[2];
#pragma unroll
    for (int kp = 0; kp < 2; ++kp)
      pa[kp] = *(const short8*)&Pb[w][kp * 512 + lo * 32 + quad * 8];
#pragma unroll
    for (int nt6 = 0; nt6 < 6; ++nt6)
#pragma unroll
      for (int kp = 0; kp < 2; ++kp) {
        const short8 vb8 =
            *(const short8*)&Vt[kp * (96 * 32) + (nt6 * 16 + lo) * 32 + quad * 8];
        O[nt6] = __builtin_amdgcn_mfma_f32_16x16x32_bf16(pa[kp], vb8, O[nt6], 0, 0, 0);
      }
    __syncthreads();   // protect Kb/Vt before next tile
  }

  // --- global key epilogue (fp32) ---
  float sg[4];
#pragma unroll
  for (int r = 0; r < 4; ++r) {
    const int row = w * 16 + quad * 4 + r;
    float part = 0.f;
#pragma unroll
    for (int i = 0; i < 6; ++i) {
      const int d = lo * 6 + i;
      part += bf2f(Qb[(d >> 5) * 2048 + row * 32 + (d & 31)]) * Kg0[d];
    }
#pragma unroll
    for (int mo = 1; mo < 16; mo <<= 1) part += __shfl_xor(part, mo);
    sg[r] = part * SCALE;
  }
#pragma unroll
  for (int r = 0; r < 4; ++r) {
    const float m_new = fmaxf(m_run[r], sg[r]);
    const float al = __expf(m_run[r] - m_new);
    const float pg = __expf(sg[r] - m_new);
    const float inv = 1.0f / (l_run[r] * al + pg);
    ushort* dst = obf + (size_t)(t0 + w * 16 + quad * 4 + r) * DMODEL + h * HD;
#pragma unroll
    for (int nt6 = 0; nt6 < 6; ++nt6) {
      const int d = nt6 * 16 + lo;
      dst[d] = f2bf((O[nt6][r] * al + pg * Vg0[d]) * inv);
    }
  }
}

// ---------------------------------------------------------------------------
// Global row, split-k partials: grid (NH, NGB); 256 keys per block.
// ---------------------------------------------------------------------------
__global__ __launch_bounds__(256) void global_attn_part(
    const float* __restrict__ qg0, const float* __restrict__ kg,
    const float* __restrict__ vg, float* __restrict__ gM,
    float* __restrict__ gL, float* __restrict__ gO) {
  const int h = blockIdx.x;
  const int g = blockIdx.y;
  const int kh = h >> 2;
  const int tid = threadIdx.x;
  const int wv = tid >> 6;
  __shared__ float q[HD];
  __shared__ float sp[256];
  __shared__ float red[4];
  __shared__ float od[2][HD];

  if (tid < HD) q[tid] = qg0[h * HD + tid];
  __syncthreads();

  const int key = g * 256 + tid;
  const float* kp = kg + (size_t)key * KVDIM + kh * HD;
  float d = 0.f;
#pragma unroll
  for (int j = 0; j < 24; ++j) {
    const f32x4 kv = *(const f32x4*)(kp + j * 4);
    const f32x4 qv = *(const f32x4*)(&q[j * 4]);
    d += qv[0] * kv[0] + qv[1] * kv[1] + qv[2] * kv[2] + qv[3] * kv[3];
  }
  d *= SCALE;

  float pm = d;
#pragma unroll
  for (int off = 32; off > 0; off >>= 1) pm = fmaxf(pm, __shfl_down(pm, off));
  if ((tid & 63) == 0) red[wv] = pm;
  __syncthreads();
  const float M = fmaxf(fmaxf(red[0], red[1]), fmaxf(red[2], red[3]));
  __syncthreads();
  const float p = __expf(d - M);
  sp[tid] = p;
  float ps = p;
#pragma unroll
  for (int off = 32; off > 0; off >>= 1) ps += __shfl_down(ps, off);
  if ((tid & 63) == 0) red[wv] = ps;
  __syncthreads();
  const float L = red[0] + red[1] + red[2] + red[3];

  if (tid < 192) {
    const int grp = tid >= HD;
    const int dd = tid - grp * HD;
    float acc = 0.f;
    const float* vp = vg + (size_t)(g * 256 + grp * 128) * KVDIM + kh * HD + dd;
#pragma unroll 4
    for (int i = 0; i < 128; ++i)
      acc = fmaf(sp[grp * 128 + i], vp[(size_t)i * KVDIM], acc);
    od[grp][dd] = acc;
  }
  __syncthreads();
  if (tid < HD) gO[((size_t)h * NGB + g) * HD + tid] = od[0][tid] + od[1][tid];
  if (tid == 0) { gM[h * NGB + g] = M; gL[h * NGB + g] = L; }
}

// ---------------------------------------------------------------------------
// Global row combine -> obf row 0 (bf16). Launch AFTER local_attn_v3.
// ---------------------------------------------------------------------------
__global__ void global_attn_comb(const float* __restrict__ gM,
                                 const float* __restrict__ gL,
                                 const float* __restrict__ gO,
                                 ushort* __restrict__ obf) {
  const int h = blockIdx.x;
  const int d = threadIdx.x;
  if (d >= HD) return;
  float M = -1e30f;
  for (int g = 0; g < NGB; ++g) M = fmaxf(M, gM[h * NGB + g]);
  float L = 0.f, O = 0.f;
  for (int g = 0; g < NGB; ++g) {
    const float e = __expf(gM[h * NGB + g] - M);
    L += gL[h * NGB + g] * e;
    O += gO[((size_t)h * NGB + g) * HD + d] * e;
  }
  obf[h * HD + d] = f2bf(O / L);
}

// ---------------------------------------------------------------------------
// Launch
// ---------------------------------------------------------------------------
extern "C" void kernel_launch(void* const* d_in, const int* in_sizes, int n_in,
                              void* d_out, int out_size, void* d_ws, size_t ws_size,
                              hipStream_t stream) {
  const float* x     = (const float*)d_in[0];
  const float* cosf  = (const float*)d_in[1];
  const float* sinf  = (const float*)d_in[2];
  const int*   pid   = (const int*)d_in[3];
  const float* W_qs  = (const float*)d_in[4];
  const float* W_ks  = (const float*)d_in[5];
  const float* W_vs  = (const float*)d_in[6];
  const float* W_qg  = (const float*)d_in[7];
  const float* W_kg  = (const float*)d_in[8];
  const float* W_vg  = (const float*)d_in[9];
  const float* W_o   = (const float*)d_in[10];
  float* out = (float*)d_out;

  char* p = (char*)d_ws;
  auto alloc = [&](size_t bytes) { char* r = p; p += (bytes + 255) & ~(size_t)255; return r; };
  float*  qs     = (float*)alloc((size_t)T_LEN * DMODEL * 4);
  float*  ksl    = (float*)alloc((size_t)T_LEN * KVDIM * 4 * 4); // ksl,vsl,kg,vg
  float*  vsl    = ksl + (size_t)T_LEN * KVDIM;
  float*  kg     = vsl + (size_t)T_LEN * KVDIM;
  float*  vg     = kg  + (size_t)T_LEN * KVDIM;
  float*  qg0    = (float*)alloc(DMODEL * 4);
  ushort* x_bf   = (ushort*)alloc((size_t)T_LEN * DMODEL * 2);
  ushort* attnbf = (ushort*)alloc((size_t)T_LEN * DMODEL * 2);
  ushort* q_bf   = (ushort*)alloc((size_t)T_LEN * DMODEL * 2);
  ushort* k_bf   = (ushort*)alloc((size_t)T_LEN * KVDIM * 2);
  ushort* v_bf   = (ushort*)alloc((size_t)T_LEN * KVDIM * 2);
  ushort* Wqs_t  = (ushort*)alloc((size_t)DMODEL * DMODEL * 2);
  ushort* Wo_t   = (ushort*)alloc((size_t)DMODEL * DMODEL * 2);
  ushort* Wsml_t = (ushort*)alloc((size_t)4 * KVDIM * DMODEL * 2);
  float*  gM     = (float*)alloc((size_t)NH * NGB * 4);
  float*  gL     = (float*)alloc((size_t)NH * NGB * 4);
  float*  gO     = (float*)alloc((size_t)NH * NGB * HD * 4);

  const dim3 blk(256);
  const int nX4 = (T_LEN * DMODEL) / 4;
  const int nV4 = (T_LEN * KVDIM) / 4;

  convert_bf16<<<(nX4 + 255) / 256, blk, 0, stream>>>(x, x_bf, nX4);
  transpose_bf16<<<dim3(DMODEL / 32, DMODEL / 32), blk, 0, stream>>>(W_qs, Wqs_t, DMODEL, DMODEL);
  transpose_bf16<<<dim3(DMODEL / 32, DMODEL / 32), blk, 0, stream>>>(W_o,  Wo_t,  DMODEL, DMODEL);
  transpose_bf16<<<dim3(KVDIM / 32, DMODEL / 32), blk, 0, stream>>>(W_ks, Wsml_t + 0 * (size_t)KVDIM * DMODEL, DMODEL, KVDIM);
  transpose_bf16<<<dim3(KVDIM / 32, DMODEL / 32), blk, 0, stream>>>(W_vs, Wsml_t + 1 * (size_t)KVDIM * DMODEL, DMODEL, KVDIM);
  transpose_bf16<<<dim3(KVDIM / 32, DMODEL / 32), blk, 0, stream>>>(W_kg, Wsml_t + 2 * (size_t)KVDIM * DMODEL, DMODEL, KVDIM);
  transpose_bf16<<<dim3(KVDIM / 32, DMODEL / 32), blk, 0, stream>>>(W_vg, Wsml_t + 3 * (size_t)KVDIM * DMODEL, DMODEL, KVDIM);

  gemm_bf16<<<dim3(DMODEL / 128, T_LEN / 128, 1), blk, 0, stream>>>(
      x_bf, Wqs_t, qs, DMODEL, DMODEL, 0, 0);
  gemm_bf16<<<dim3(KVDIM / 128, T_LEN / 128, 4), blk, 0, stream>>>(
      x_bf, Wsml_t, ksl, KVDIM, DMODEL,
      (size_t)KVDIM * DMODEL, (size_t)T_LEN * KVDIM);
  qg0_kernel<<<(DMODEL + 255) / 256, blk, 0, stream>>>(x, W_qg, qg0);

  {
    const int tq = T_LEN * NH * NFREQ;
    const int tk = T_LEN * NKV * NFREQ;
    rope_conv<<<(tq + 255) / 256, blk, 0, stream>>>(qs,  q_bf, cosf, sinf, pid, T_LEN, NH);
    rope_conv<<<(tk + 255) / 256, blk, 0, stream>>>(ksl, k_bf, cosf, sinf, pid, T_LEN, NKV);
    rope_ip<<<(tk + 255) / 256, blk, 0, stream>>>(kg, cosf, sinf, pid, T_LEN, NKV);
    rope_ip<<<(NH * NFREQ + 255) / 256, blk, 0, stream>>>(qg0, cosf, sinf, pid, 1, NH);
    convert_bf16<<<(nV4 + 255) / 256, blk, 0, stream>>>(vsl, v_bf, nV4);
  }

  local_attn_v3<<<dim3(T_LEN / 64, NH), blk, 0, stream>>>(
      q_bf, k_bf, v_bf, kg, vg, attnbf);
  global_attn_part<<<dim3(NH, NGB), blk, 0, stream>>>(qg0, kg, vg, gM, gL, gO);
  global_attn_comb<<<NH, dim3(128), 0, stream>>>(gM, gL, gO, attnbf);

  gemm_bf16<<<dim3(DMODEL / 128, T_LEN / 128, 1), blk, 0, stream>>>(
      attnbf, Wo_t, out, DMODEL, DMODEL, 0, 0);
}

// Round 6
// 477.869 us; speedup vs baseline: 8.9552x; 1.2779x over previous
//
#include <hip/hip_runtime.h>

// Problem constants
#define T_LEN 8192
#define DMODEL 1536
#define NH 16
#define NKV 4
#define HD 96
#define KVDIM (NKV * HD)   // 384
#define W2 256             // WINDOW/2
#define NFREQ 48           // HD/2
#define NGB 32             // global-attention split-k blocks per head

static constexpr float SCALE = 0.10206207261596577f; // 1/sqrt(96)

typedef float f32x4 __attribute__((ext_vector_type(4)));
typedef float f32x2 __attribute__((ext_vector_type(2)));
typedef short short8 __attribute__((ext_vector_type(8)));
typedef unsigned short ushort;

__device__ __forceinline__ ushort f2bf(float f) {
  unsigned int x = __float_as_uint(f);
  return (ushort)((x + 0x7FFFu + ((x >> 16) & 1u)) >> 16);
}
__device__ __forceinline__ float bf2f(ushort u) {
  return __uint_as_float((unsigned int)u << 16);
}
__device__ __forceinline__ void load_lds16(const void* g, void* l) {
  __builtin_amdgcn_global_load_lds(
      (const __attribute__((address_space(1))) void*)g,
      (__attribute__((address_space(3))) void*)l, 16, 0, 0);
}

// ---------------------------------------------------------------------------
// Elementwise fp32 -> bf16 (n4 = n/4)
// ---------------------------------------------------------------------------
__global__ __launch_bounds__(256) void convert_bf16(
    const float* __restrict__ in, ushort* __restrict__ out, int n4) {
  const int i = blockIdx.x * 256 + threadIdx.x;
  if (i >= n4) return;
  const f32x4 v = *(const f32x4*)&in[i * 4];
  ushort o[4] = {f2bf(v[0]), f2bf(v[1]), f2bf(v[2]), f2bf(v[3])};
  *(unsigned long long*)&out[i * 4] =
      (unsigned long long)o[0] | ((unsigned long long)o[1] << 16) |
      ((unsigned long long)o[2] << 32) | ((unsigned long long)o[3] << 48);
}

// ---------------------------------------------------------------------------
// W[K][N] fp32 -> Wt[N][K] bf16
// ---------------------------------------------------------------------------
__global__ __launch_bounds__(256) void transpose_bf16(
    const float* __restrict__ W, ushort* __restrict__ Wt, int K, int N) {
  __shared__ ushort tile[32][33];
  const int tx = threadIdx.x & 31;
  const int ty = threadIdx.x >> 5;
  const int n0 = blockIdx.x * 32;
  const int k0 = blockIdx.y * 32;
#pragma unroll
  for (int i = 0; i < 32; i += 8)
    tile[tx][ty + i] = f2bf(W[(size_t)(k0 + ty + i) * N + n0 + tx]);
  __syncthreads();
#pragma unroll
  for (int i = 0; i < 32; i += 8)
    Wt[(size_t)(n0 + ty + i) * K + k0 + tx] = tile[ty + i][tx];
}

// ---------------------------------------------------------------------------
// bf16 MFMA GEMM (m97 structure): C[M,N] = A @ Bt^T, fp32 out.
// ---------------------------------------------------------------------------
__global__ __launch_bounds__(256) void gemm_bf16(
    const ushort* __restrict__ A, const ushort* __restrict__ Bt,
    float* __restrict__ C, int N, int K,
    size_t strideBt, size_t strideC) {
  __shared__ ushort Abuf[128 * 32];
  __shared__ ushort Bbuf[128 * 32];

  const ushort* BtZ = Bt + (size_t)blockIdx.z * strideBt;
  float* Cz = C + (size_t)blockIdx.z * strideC;

  const int tid  = threadIdx.x;
  const int wave = tid >> 6;
  const int lane = tid & 63;
  const int lo   = lane & 15;
  const int quad = lane >> 4;
  const int m0 = blockIdx.y * 128;
  const int n0 = blockIdx.x * 128;
  const int mw = (wave & 1) * 64;
  const int nw = (wave >> 1) * 64;

  f32x4 acc[4][4];
#pragma unroll
  for (int i = 0; i < 4; ++i)
#pragma unroll
    for (int j = 0; j < 4; ++j) acc[i][j] = {0.f, 0.f, 0.f, 0.f};

  for (int kt = 0; kt < K; kt += 32) {
#pragma unroll
    for (int j = 0; j < 2; ++j) {
      const int c = wave * 128 + j * 64 + lane;
      const int row = c >> 2;
      const int colb = (c & 3) << 4;
      const int ldsOff = (wave * 128 + j * 64) * 16;
      load_lds16((const char*)A + ((size_t)(m0 + row) * K + kt) * 2 + colb,
                 (char*)Abuf + ldsOff);
      load_lds16((const char*)BtZ + ((size_t)(n0 + row) * K + kt) * 2 + colb,
                 (char*)Bbuf + ldsOff);
    }
    __syncthreads();

    short8 af[4], bfr[4];
#pragma unroll
    for (int mt = 0; mt < 4; ++mt)
      af[mt] = *(const short8*)&Abuf[(mw + mt * 16 + lo) * 32 + quad * 8];
#pragma unroll
    for (int nt = 0; nt < 4; ++nt)
      bfr[nt] = *(const short8*)&Bbuf[(nw + nt * 16 + lo) * 32 + quad * 8];
#pragma unroll
    for (int mt = 0; mt < 4; ++mt)
#pragma unroll
      for (int nt = 0; nt < 4; ++nt)
        acc[mt][nt] = __builtin_amdgcn_mfma_f32_16x16x32_bf16(
            af[mt], bfr[nt], acc[mt][nt], 0, 0, 0);
    __syncthreads();
  }

#pragma unroll
  for (int mt = 0; mt < 4; ++mt) {
    const int r0 = m0 + mw + mt * 16 + quad * 4;
#pragma unroll
    for (int nt = 0; nt < 4; ++nt) {
      const int cc = n0 + nw + nt * 16 + lo;
#pragma unroll
      for (int r = 0; r < 4; ++r)
        Cz[(size_t)(r0 + r) * N + cc] = acc[mt][nt][r];
    }
  }
}

// ---------------------------------------------------------------------------
// qg row 0: split-k. Grid (DMODEL/256, DMODEL/128); atomicAdd partials.
// ---------------------------------------------------------------------------
__global__ void qg0_zero(float* __restrict__ qg0) {
  qg0[blockIdx.x * 256 + threadIdx.x] = 0.f;
}
__global__ __launch_bounds__(256) void qg0_split(
    const float* __restrict__ x, const float* __restrict__ W,
    float* __restrict__ qg0) {
  const int j = blockIdx.x * 256 + threadIdx.x;
  const int k0 = blockIdx.y * 128;
  float acc = 0.f;
#pragma unroll 8
  for (int k = k0; k < k0 + 128; ++k)
    acc = fmaf(x[k], W[(size_t)k * DMODEL + j], acc);
  atomicAdd(&qg0[j], acc);
}

// ---------------------------------------------------------------------------
// In-place interleaved RoPE (fp32)
// ---------------------------------------------------------------------------
__global__ void rope_ip(float* __restrict__ arr,
                        const float* __restrict__ cosf,
                        const float* __restrict__ sinf,
                        const int* __restrict__ pid, int T, int H) {
  const int idx = blockIdx.x * 256 + threadIdx.x;
  const int total = T * H * NFREQ;
  if (idx >= total) return;
  const int i = idx % NFREQ;
  const int th = idx / NFREQ;
  const int t = th / H;
  const int p = pid[t];
  const float c = cosf[(size_t)p * NFREQ + i];
  const float s = sinf[(size_t)p * NFREQ + i];
  const size_t base = (size_t)th * HD + 2 * i;
  const float e = arr[base];
  const float o = arr[base + 1];
  arr[base]     = e * c - o * s;
  arr[base + 1] = e * s + o * c;
}

// ---------------------------------------------------------------------------
// RoPE fp32 src -> bf16 dst
// ---------------------------------------------------------------------------
__global__ void rope_conv(const float* __restrict__ src,
                          ushort* __restrict__ dst,
                          const float* __restrict__ cosf,
                          const float* __restrict__ sinf,
                          const int* __restrict__ pid, int T, int H) {
  const int idx = blockIdx.x * 256 + threadIdx.x;
  const int total = T * H * NFREQ;
  if (idx >= total) return;
  const int i = idx % NFREQ;
  const int th = idx / NFREQ;
  const int t = th / H;
  const int p = pid[t];
  const float c = cosf[(size_t)p * NFREQ + i];
  const float s = sinf[(size_t)p * NFREQ + i];
  const size_t base = (size_t)th * HD + 2 * i;
  const float e = src[base];
  const float o = src[base + 1];
  const float re = e * c - o * s;
  const float ro = e * s + o * c;
  *(unsigned int*)&dst[base] =
      (unsigned int)f2bf(re) | ((unsigned int)f2bf(ro) << 16);
}

// ---------------------------------------------------------------------------
// Local attention v3: MFMA bf16 flash tiles (verified round 5).
// ---------------------------------------------------------------------------
__global__ __launch_bounds__(256) void local_attn_v3(
    const ushort* __restrict__ qbf, const ushort* __restrict__ kbf,
    const ushort* __restrict__ vbf, const float* __restrict__ kg,
    const float* __restrict__ vg, ushort* __restrict__ obf) {
  __shared__ ushort Qb[3 * 64 * 32];
  __shared__ ushort Kb[3 * 64 * 32];
  __shared__ ushort Vt[2 * 96 * 32];
  __shared__ ushort Pb[4][2 * 16 * 32];
  __shared__ float Kg0[HD];
  __shared__ float Vg0[HD];

  const int t0 = blockIdx.x * 64;
  const int h  = blockIdx.y;
  const int kh = h >> 2;
  const int tid = threadIdx.x;
  const int w    = tid >> 6;
  const int lane = tid & 63;
  const int lo   = lane & 15;
  const int quad = lane >> 4;

  {
    const int rem = w * 64 + lane;
    const int row = rem >> 2;
    const int sub = (rem & 3) * 8;
#pragma unroll
    for (int j = 0; j < 3; ++j) {
      load_lds16(qbf + (size_t)(t0 + row) * DMODEL + h * HD + j * 32 + sub,
                 (char*)Qb + (j * 256 + w * 64) * 16);
    }
  }
  if (tid < HD) {
    Kg0[tid] = kg[kh * HD + tid];
    Vg0[tid] = vg[kh * HD + tid];
  }

  f32x4 O[6];
#pragma unroll
  for (int i = 0; i < 6; ++i) O[i] = {0.f, 0.f, 0.f, 0.f};
  float m_run[4], l_run[4];
#pragma unroll
  for (int r = 0; r < 4; ++r) { m_run[r] = -1e30f; l_run[r] = 0.f; }

  __syncthreads();

  for (int ti = 0; ti < 5; ++ti) {
    const int kb = t0 - W2 + ti * 64;
    if (kb < 0) continue;

    {
      const int rem = w * 64 + lane;
      const int row = rem >> 2;
      const int sub = (rem & 3) * 8;
#pragma unroll
      for (int j = 0; j < 3; ++j) {
        load_lds16(kbf + (size_t)(kb + row) * KVDIM + kh * HD + j * 32 + sub,
                   (char*)Kb + (j * 256 + w * 64) * 16);
      }
      const int key = tid & 63;
      const int dg  = tid >> 6;
      const ushort* vsrc = vbf + (size_t)(kb + key) * KVDIM + kh * HD + dg * 24;
      short8 v0 = *(const short8*)(vsrc);
      short8 v1 = *(const short8*)(vsrc + 8);
      short8 v2 = *(const short8*)(vsrc + 16);
      const int vbase = (key >> 5) * (96 * 32) + (key & 31);
#pragma unroll
      for (int i = 0; i < 8; ++i) {
        Vt[vbase + (dg * 24 + i) * 32]      = (ushort)v0[i];
        Vt[vbase + (dg * 24 + 8 + i) * 32]  = (ushort)v1[i];
        Vt[vbase + (dg * 24 + 16 + i) * 32] = (ushort)v2[i];
      }
    }
    __syncthreads();

    short8 af[3];
#pragma unroll
    for (int p = 0; p < 3; ++p)
      af[p] = *(const short8*)&Qb[p * 2048 + (w * 16 + lo) * 32 + quad * 8];
    f32x4 s4[4];
#pragma unroll
    for (int nt = 0; nt < 4; ++nt) s4[nt] = {0.f, 0.f, 0.f, 0.f};
#pragma unroll
    for (int nt = 0; nt < 4; ++nt)
#pragma unroll
      for (int p = 0; p < 3; ++p) {
        const short8 bf8 =
            *(const short8*)&Kb[p * 2048 + (nt * 16 + lo) * 32 + quad * 8];
        s4[nt] = __builtin_amdgcn_mfma_f32_16x16x32_bf16(af[p], bf8, s4[nt], 0, 0, 0);
      }

    float alpha[4];
#pragma unroll
    for (int r = 0; r < 4; ++r) {
      const int tq = t0 + w * 16 + quad * 4 + r;
      float sv[4], rm = -1e30f;
#pragma unroll
      for (int nt = 0; nt < 4; ++nt) {
        const int p = kb + nt * 16 + lo;
        const bool ok = (p >= 1) && (p <= tq) && (p + W2 >= tq);
        sv[nt] = ok ? s4[nt][r] * SCALE : -1e30f;
        rm = fmaxf(rm, sv[nt]);
      }
#pragma unroll
      for (int mo = 1; mo < 16; mo <<= 1) rm = fmaxf(rm, __shfl_xor(rm, mo));
      const float m_new = fmaxf(m_run[r], rm);
      float psum = 0.f;
#pragma unroll
      for (int nt = 0; nt < 4; ++nt) {
        const float pv = (sv[nt] > -1e29f) ? __expf(sv[nt] - m_new) : 0.f;
        Pb[w][(nt >> 1) * 512 + (quad * 4 + r) * 32 + (nt & 1) * 16 + lo] = f2bf(pv);
        psum += pv;
      }
#pragma unroll
      for (int mo = 1; mo < 16; mo <<= 1) psum += __shfl_xor(psum, mo);
      alpha[r] = __expf(m_run[r] - m_new);
      l_run[r] = l_run[r] * alpha[r] + psum;
      m_run[r] = m_new;
    }

#pragma unroll
    for (int nt6 = 0; nt6 < 6; ++nt6)
#pragma unroll
      for (int r = 0; r < 4; ++r) O[nt6][r] *= alpha[r];

    short8 pa[2];
#pragma unroll
    for (int kp = 0; kp < 2; ++kp)
      pa[kp] = *(const short8*)&Pb[w][kp * 512 + lo * 32 + quad * 8];
#pragma unroll
    for (int nt6 = 0; nt6 < 6; ++nt6)
#pragma unroll
      for (int kp = 0; kp < 2; ++kp) {
        const short8 vb8 =
            *(const short8*)&Vt[kp * (96 * 32) + (nt6 * 16 + lo) * 32 + quad * 8];
        O[nt6] = __builtin_amdgcn_mfma_f32_16x16x32_bf16(pa[kp], vb8, O[nt6], 0, 0, 0);
      }
    __syncthreads();
  }

  float sg[4];
#pragma unroll
  for (int r = 0; r < 4; ++r) {
    const int row = w * 16 + quad * 4 + r;
    float part = 0.f;
#pragma unroll
    for (int i = 0; i < 6; ++i) {
      const int d = lo * 6 + i;
      part += bf2f(Qb[(d >> 5) * 2048 + row * 32 + (d & 31)]) * Kg0[d];
    }
#pragma unroll
    for (int mo = 1; mo < 16; mo <<= 1) part += __shfl_xor(part, mo);
    sg[r] = part * SCALE;
  }
#pragma unroll
  for (int r = 0; r < 4; ++r) {
    const float m_new = fmaxf(m_run[r], sg[r]);
    const float al = __expf(m_run[r] - m_new);
    const float pg = __expf(sg[r] - m_new);
    const float inv = 1.0f / (l_run[r] * al + pg);
    ushort* dst = obf + (size_t)(t0 + w * 16 + quad * 4 + r) * DMODEL + h * HD;
#pragma unroll
    for (int nt6 = 0; nt6 < 6; ++nt6) {
      const int d = nt6 * 16 + lo;
      dst[d] = f2bf((O[nt6][r] * al + pg * Vg0[d]) * inv);
    }
  }
}

// ---------------------------------------------------------------------------
// Global row, split-k partials: grid (NH, NGB); 256 keys per block.
// ---------------------------------------------------------------------------
__global__ __launch_bounds__(256) void global_attn_part(
    const float* __restrict__ qg0, const float* __restrict__ kg,
    const float* __restrict__ vg, float* __restrict__ gM,
    float* __restrict__ gL, float* __restrict__ gO) {
  const int h = blockIdx.x;
  const int g = blockIdx.y;
  const int kh = h >> 2;
  const int tid = threadIdx.x;
  const int wv = tid >> 6;
  __shared__ float q[HD];
  __shared__ float sp[256];
  __shared__ float red[4];
  __shared__ float od[2][HD];

  if (tid < HD) q[tid] = qg0[h * HD + tid];
  __syncthreads();

  const int key = g * 256 + tid;
  const float* kp = kg + (size_t)key * KVDIM + kh * HD;
  float d = 0.f;
#pragma unroll
  for (int j = 0; j < 24; ++j) {
    const f32x4 kv = *(const f32x4*)(kp + j * 4);
    const f32x4 qv = *(const f32x4*)(&q[j * 4]);
    d += qv[0] * kv[0] + qv[1] * kv[1] + qv[2] * kv[2] + qv[3] * kv[3];
  }
  d *= SCALE;

  float pm = d;
#pragma unroll
  for (int off = 32; off > 0; off >>= 1) pm = fmaxf(pm, __shfl_down(pm, off));
  if ((tid & 63) == 0) red[wv] = pm;
  __syncthreads();
  const float M = fmaxf(fmaxf(red[0], red[1]), fmaxf(red[2], red[3]));
  __syncthreads();
  const float p = __expf(d - M);
  sp[tid] = p;
  float ps = p;
#pragma unroll
  for (int off = 32; off > 0; off >>= 1) ps += __shfl_down(ps, off);
  if ((tid & 63) == 0) red[wv] = ps;
  __syncthreads();
  const float L = red[0] + red[1] + red[2] + red[3];

  if (tid < 192) {
    const int grp = tid >= HD;
    const int dd = tid - grp * HD;
    float acc = 0.f;
    const float* vp = vg + (size_t)(g * 256 + grp * 128) * KVDIM + kh * HD + dd;
#pragma unroll 4
    for (int i = 0; i < 128; ++i)
      acc = fmaf(sp[grp * 128 + i], vp[(size_t)i * KVDIM], acc);
    od[grp][dd] = acc;
  }
  __syncthreads();
  if (tid < HD) gO[((size_t)h * NGB + g) * HD + tid] = od[0][tid] + od[1][tid];
  if (tid == 0) { gM[h * NGB + g] = M; gL[h * NGB + g] = L; }
}

// ---------------------------------------------------------------------------
// Global row combine -> obf row 0 (bf16). Launch AFTER local_attn_v3.
// ---------------------------------------------------------------------------
__global__ void global_attn_comb(const float* __restrict__ gM,
                                 const float* __restrict__ gL,
                                 const float* __restrict__ gO,
                                 ushort* __restrict__ obf) {
  const int h = blockIdx.x;
  const int d = threadIdx.x;
  if (d >= HD) return;
  float M = -1e30f;
  for (int g = 0; g < NGB; ++g) M = fmaxf(M, gM[h * NGB + g]);
  float L = 0.f, O = 0.f;
  for (int g = 0; g < NGB; ++g) {
    const float e = __expf(gM[h * NGB + g] - M);
    L += gL[h * NGB + g] * e;
    O += gO[((size_t)h * NGB + g) * HD + d] * e;
  }
  obf[h * HD + d] = f2bf(O / L);
}

// ---------------------------------------------------------------------------
// Launch
// ---------------------------------------------------------------------------
extern "C" void kernel_launch(void* const* d_in, const int* in_sizes, int n_in,
                              void* d_out, int out_size, void* d_ws, size_t ws_size,
                              hipStream_t stream) {
  const float* x     = (const float*)d_in[0];
  const float* cosf  = (const float*)d_in[1];
  const float* sinf  = (const float*)d_in[2];
  const int*   pid   = (const int*)d_in[3];
  const float* W_qs  = (const float*)d_in[4];
  const float* W_ks  = (const float*)d_in[5];
  const float* W_vs  = (const float*)d_in[6];
  const float* W_qg  = (const float*)d_in[7];
  const float* W_kg  = (const float*)d_in[8];
  const float* W_vg  = (const float*)d_in[9];
  const float* W_o   = (const float*)d_in[10];
  float* out = (float*)d_out;

  char* p = (char*)d_ws;
  auto alloc = [&](size_t bytes) { char* r = p; p += (bytes + 255) & ~(size_t)255; return r; };
  float*  qs     = (float*)alloc((size_t)T_LEN * DMODEL * 4);
  float*  ksl    = (float*)alloc((size_t)T_LEN * KVDIM * 4 * 4); // ksl,vsl,kg,vg
  float*  vsl    = ksl + (size_t)T_LEN * KVDIM;
  float*  kg     = vsl + (size_t)T_LEN * KVDIM;
  float*  vg     = kg  + (size_t)T_LEN * KVDIM;
  float*  qg0    = (float*)alloc(DMODEL * 4);
  ushort* x_bf   = (ushort*)alloc((size_t)T_LEN * DMODEL * 2);
  ushort* attnbf = (ushort*)alloc((size_t)T_LEN * DMODEL * 2);
  ushort* q_bf   = (ushort*)alloc((size_t)T_LEN * DMODEL * 2);
  ushort* k_bf   = (ushort*)alloc((size_t)T_LEN * KVDIM * 2);
  ushort* v_bf   = (ushort*)alloc((size_t)T_LEN * KVDIM * 2);
  ushort* Wqs_t  = (ushort*)alloc((size_t)DMODEL * DMODEL * 2);
  ushort* Wo_t   = (ushort*)alloc((size_t)DMODEL * DMODEL * 2);
  ushort* Wsml_t = (ushort*)alloc((size_t)4 * KVDIM * DMODEL * 2);
  float*  gM     = (float*)alloc((size_t)NH * NGB * 4);
  float*  gL     = (float*)alloc((size_t)NH * NGB * 4);
  float*  gO     = (float*)alloc((size_t)NH * NGB * HD * 4);

  const dim3 blk(256);
  const int nX4 = (T_LEN * DMODEL) / 4;
  const int nV4 = (T_LEN * KVDIM) / 4;

  convert_bf16<<<(nX4 + 255) / 256, blk, 0, stream>>>(x, x_bf, nX4);
  transpose_bf16<<<dim3(DMODEL / 32, DMODEL / 32), blk, 0, stream>>>(W_qs, Wqs_t, DMODEL, DMODEL);
  transpose_bf16<<<dim3(DMODEL / 32, DMODEL / 32), blk, 0, stream>>>(W_o,  Wo_t,  DMODEL, DMODEL);
  transpose_bf16<<<dim3(KVDIM / 32, DMODEL / 32), blk, 0, stream>>>(W_ks, Wsml_t + 0 * (size_t)KVDIM * DMODEL, DMODEL, KVDIM);
  transpose_bf16<<<dim3(KVDIM / 32, DMODEL / 32), blk, 0, stream>>>(W_vs, Wsml_t + 1 * (size_t)KVDIM * DMODEL, DMODEL, KVDIM);
  transpose_bf16<<<dim3(KVDIM / 32, DMODEL / 32), blk, 0, stream>>>(W_kg, Wsml_t + 2 * (size_t)KVDIM * DMODEL, DMODEL, KVDIM);
  transpose_bf16<<<dim3(KVDIM / 32, DMODEL / 32), blk, 0, stream>>>(W_vg, Wsml_t + 3 * (size_t)KVDIM * DMODEL, DMODEL, KVDIM);

  gemm_bf16<<<dim3(DMODEL / 128, T_LEN / 128, 1), blk, 0, stream>>>(
      x_bf, Wqs_t, qs, DMODEL, DMODEL, 0, 0);
  gemm_bf16<<<dim3(KVDIM / 128, T_LEN / 128, 4), blk, 0, stream>>>(
      x_bf, Wsml_t, ksl, KVDIM, DMODEL,
      (size_t)KVDIM * DMODEL, (size_t)T_LEN * KVDIM);

  // qg row 0: zero + split-k (72 blocks). RoPE at pos 0 is identity -> skipped.
  qg0_zero<<<DMODEL / 256, blk, 0, stream>>>(qg0);
  qg0_split<<<dim3(DMODEL / 256, DMODEL / 128), blk, 0, stream>>>(x, W_qg, qg0);

  {
    const int tq = T_LEN * NH * NFREQ;
    const int tk = T_LEN * NKV * NFREQ;
    rope_conv<<<(tq + 255) / 256, blk, 0, stream>>>(qs,  q_bf, cosf, sinf, pid, T_LEN, NH);
    rope_conv<<<(tk + 255) / 256, blk, 0, stream>>>(ksl, k_bf, cosf, sinf, pid, T_LEN, NKV);
    rope_ip<<<(tk + 255) / 256, blk, 0, stream>>>(kg, cosf, sinf, pid, T_LEN, NKV);
    convert_bf16<<<(nV4 + 255) / 256, blk, 0, stream>>>(vsl, v_bf, nV4);
  }

  local_attn_v3<<<dim3(T_LEN / 64, NH), blk, 0, stream>>>(
      q_bf, k_bf, v_bf, kg, vg, attnbf);
  global_attn_part<<<dim3(NH, NGB), blk, 0, stream>>>(qg0, kg, vg, gM, gL, gO);
  global_attn_comb<<<NH, dim3(128), 0, stream>>>(gM, gL, gO, attnbf);

  gemm_bf16<<<dim3(DMODEL / 128, T_LEN / 128, 1), blk, 0, stream>>>(
      attnbf, Wo_t, out, DMODEL, DMODEL, 0, 0);
}